// Round 1
// baseline (53110.315 us; speedup 1.0000x reference)
//
#include <hip/hip_runtime.h>
#include <hip/hip_cooperative_groups.h>
#include <math.h>

namespace cg = cooperative_groups;

#define BB 32
#define LL 512
#define EE 512
#define HH 1024
#define VV 32000
#define TT 64
#define G4 4096
#define NPRED 33024  // VV + HH
#define NBLK 516     // persistent grid: 516 blocks (= pred gemm 129 nt x 4 ks)

__device__ __forceinline__ float fast_tanh(float x){
  float ax = fabsf(x);
  float e = __expf(ax + ax);
  float r = 1.0f - 2.0f/(e + 1.0f);
  return copysignf(r, x);
}

// ---------------- init ----------------
__global__ void k_init(float* __restrict__ outp, float* __restrict__ a0t,
                       float* __restrict__ a1t, float* __restrict__ c0,
                       float* __restrict__ c1, float* __restrict__ q,
                       const float* __restrict__ bad, int* __restrict__ token,
                       const int* __restrict__ trg, const int* __restrict__ sosp,
                       float* __restrict__ predout){
  int idx = blockIdx.x*256 + threadIdx.x;
  if (idx < 1024000){ int b = idx / VV; int v = idx % VV;
    outp[(size_t)b*TT*VV + v] = 0.f; return; }
  idx -= 1024000;
  if (idx < 49152){ a0t[idx]=0.f; return; } idx -= 49152;
  if (idx < 65536){ a1t[idx]=0.f; return; } idx -= 65536;
  if (idx < 32768){ c0[idx]=0.f; return; } idx -= 32768;
  if (idx < 32768){ c1[idx]=0.f; return; } idx -= 32768;
  if (idx < 32768){ q[idx] = bad[idx & (HH-1)]; return; } idx -= 32768;
  if (idx < 32){ token[idx] = trg[idx*TT]; return; } idx -= 32;
  if (idx < 32){ predout[idx*TT] = (float)(*sosp); return; }
}

// ---------------- generic transpose: dst[c*ds + r] = src[r*ss + c] ----------
__global__ void k_transpose(const float* __restrict__ src, int ss,
                            float* __restrict__ dst, int ds, int R, int C){
  __shared__ float tile[32][33];
  int c0 = blockIdx.x*32, r0 = blockIdx.y*32;
  int tx = threadIdx.x, ty = threadIdx.y;  // (32,8)
  #pragma unroll
  for (int i=0;i<32;i+=8)
    tile[ty+i][tx] = src[(size_t)(r0+ty+i)*ss + c0+tx];
  __syncthreads();
  #pragma unroll
  for (int i=0;i<32;i+=8)
    dst[(size_t)(c0+ty+i)*ds + r0+tx] = tile[tx][ty+i];
}

// ---------------- precompute GEMM: C[m][n] = sum_k AT[k][m]*WT[k][n] (+bias)
__global__ __launch_bounds__(256) void k_pregemm(const float* __restrict__ AT,
    const float* __restrict__ WT, const float* __restrict__ bias,
    float* __restrict__ Cout, int N, int Kdim){
  int mt = blockIdx.x, ntg = blockIdx.y;
  int w = threadIdx.x >> 6, lane = threadIdx.x & 63;
  int m = mt*64 + lane;
  int nbase = ntg*128 + w*32;
  float acc[32];
  #pragma unroll
  for (int j=0;j<32;j++) acc[j]=0.f;
  const float* ap = AT + m;
  const float* wp = WT + nbase;
  for (int k=0;k<Kdim;k++){
    float a = ap[(size_t)k*16384];
    const float4* w4 = (const float4*)(wp + (size_t)k*N);
    #pragma unroll
    for (int j4=0;j4<8;j4++){
      float4 wv = w4[j4];
      acc[j4*4+0] = fmaf(a, wv.x, acc[j4*4+0]);
      acc[j4*4+1] = fmaf(a, wv.y, acc[j4*4+1]);
      acc[j4*4+2] = fmaf(a, wv.z, acc[j4*4+2]);
      acc[j4*4+3] = fmaf(a, wv.w, acc[j4*4+3]);
    }
  }
  __shared__ float tile[64][133];
  #pragma unroll
  for (int j=0;j<32;j++){
    float bv = bias ? bias[nbase+j] : 0.f;
    tile[lane][w*32+j] = acc[j] + bv;
  }
  __syncthreads();
  #pragma unroll
  for (int i=0;i<32;i++){
    int flat = i*256 + threadIdx.x;
    int mm = flat >> 7, nn = flat & 127;
    Cout[(size_t)(mt*64+mm)*N + ntg*128 + nn] = tile[mm][nn];
  }
}

// =================== OLD per-step kernels (fallback path) ===================
__global__ __launch_bounds__(256) void k_score(const float* __restrict__ ep,
    const float* __restrict__ partP, const float* __restrict__ bad,
    const float* __restrict__ vatt, float* __restrict__ scores,
    const float* __restrict__ argv, const int* __restrict__ argi,
    int* __restrict__ token, float* __restrict__ predout, int t){
  int b = blockIdx.x, lt = blockIdx.y;
  int w = threadIdx.x >> 6, lane = threadIdx.x & 63;
  __shared__ float qs[HH], vs[HH];
  for (int i=threadIdx.x; i<HH; i+=256){
    float qv = bad[i];
    if (t > 1){
      qv += partP[(size_t)b*NPRED + VV + i]
          + partP[(size_t)(32+b)*NPRED + VV + i];
    }
    qs[i] = qv;
    vs[i] = vatt[i];
  }
  __syncthreads();
  if (lt==0 && t>1 && w==0){
    float bv = -INFINITY; int bi = 0x7fffffff;
    for (int j=lane; j<500; j+=64){
      float v = argv[j*32 + b]; int ix = argi[j*32 + b];
      if (v > bv || (v==bv && ix < bi)){ bv=v; bi=ix; }
    }
    #pragma unroll
    for (int d=32; d>0; d>>=1){
      float ov = __shfl_down(bv, d); int oi = __shfl_down(bi, d);
      if (ov > bv || (ov==bv && oi < bi)){ bv=ov; bi=oi; }
    }
    if (lane==0){ token[b]=bi; predout[b*TT + (t-1)] = (float)bi; }
  }
  #pragma unroll
  for (int i=0;i<8;i++){
    int l = lt*32 + w*8 + i;
    const float4* row = (const float4*)(ep + ((size_t)(b*LL + l))*HH);
    float acc = 0.f;
    #pragma unroll
    for (int c=0;c<4;c++){
      float4 xv = row[c*64 + lane];
      float4 qv = ((const float4*)qs)[c*64 + lane];
      float4 vv = ((const float4*)vs)[c*64 + lane];
      acc += fast_tanh(xv.x+qv.x)*vv.x;
      acc += fast_tanh(xv.y+qv.y)*vv.y;
      acc += fast_tanh(xv.z+qv.z)*vv.z;
      acc += fast_tanh(xv.w+qv.w)*vv.w;
    }
    #pragma unroll
    for (int d=32; d>0; d>>=1) acc += __shfl_down(acc, d);
    if (lane==0) scores[b*LL + l] = acc;
  }
}

__global__ __launch_bounds__(256) void k_attnx(const float* __restrict__ scores,
    const float* __restrict__ encW2, const float* __restrict__ emb,
    const int* __restrict__ token, const float* __restrict__ W1T,
    const float* __restrict__ b_in, float* __restrict__ A0T){
  int b = blockIdx.x, et = blockIdx.y;
  int tx = threadIdx.x;
  int w = tx >> 6, lane = tx & 63;
  __shared__ float alpha[LL];
  __shared__ float embs[EE];
  __shared__ float red[8];
  __shared__ float comb[4][64];
  float s0 = scores[b*LL + tx], s1 = scores[b*LL + 256 + tx];
  float mx = fmaxf(s0, s1);
  #pragma unroll
  for (int d=32; d>0; d>>=1) mx = fmaxf(mx, __shfl_down(mx, d));
  if ((tx&63)==0) red[tx>>6] = mx;
  __syncthreads();
  mx = fmaxf(fmaxf(red[0],red[1]), fmaxf(red[2],red[3]));
  float e0 = __expf(s0-mx), e1 = __expf(s1-mx);
  float sm = e0+e1;
  #pragma unroll
  for (int d=32; d>0; d>>=1) sm += __shfl_down(sm, d);
  if ((tx&63)==0) red[4+(tx>>6)] = sm;
  __syncthreads();
  sm = red[4]+red[5]+red[6]+red[7];
  float inv = 1.0f/sm;
  alpha[tx] = e0*inv; alpha[tx+256] = e1*inv;
  int tok = token[b];
  embs[tx] = emb[(size_t)tok*EE + tx];
  embs[tx+256] = emb[(size_t)tok*EE + 256 + tx];
  __syncthreads();
  int e = et*64 + lane;
  float acc = 0.f;
  const float* cw = encW2 + (size_t)b*LL*EE + (size_t)w*128*EE + e;
  #pragma unroll 4
  for (int l=0;l<128;l++) acc = fmaf(alpha[w*128+l], cw[(size_t)l*EE], acc);
  const float* wp = W1T + (size_t)w*128*EE + e;
  #pragma unroll 4
  for (int j=0;j<128;j++) acc = fmaf(embs[w*128+j], wp[(size_t)j*EE], acc);
  comb[w][lane] = acc;
  __syncthreads();
  if (w==0){
    float r = comb[0][lane]+comb[1][lane]+comb[2][lane]+comb[3][lane] + b_in[e];
    A0T[e*32 + b] = r;
  }
}

__global__ __launch_bounds__(256) void k_gemm_smallM(const float* __restrict__ AT,
    const float* __restrict__ WT, float* __restrict__ partial,
    int N, int kslice){
  int nt = blockIdx.x, ks = blockIdx.y;
  int w = threadIdx.x >> 6, lane = threadIdx.x & 63;
  int n0 = nt*256 + lane*4;
  int b0 = w*8;
  int k0 = ks*kslice;
  float acc[8][4];
  #pragma unroll
  for (int i=0;i<8;i++)
    #pragma unroll
    for (int j=0;j<4;j++) acc[i][j]=0.f;
  const float* wp = WT + (size_t)k0*N + n0;
  const float* ap = AT + (size_t)k0*32 + b0;
  #pragma unroll 4
  for (int k=0;k<kslice;k++){
    float4 wv = *(const float4*)(wp);
    float4 a0 = *(const float4*)(ap);
    float4 a1 = *(const float4*)(ap+4);
    wp += N; ap += 32;
    acc[0][0]=fmaf(a0.x,wv.x,acc[0][0]); acc[0][1]=fmaf(a0.x,wv.y,acc[0][1]);
    acc[0][2]=fmaf(a0.x,wv.z,acc[0][2]); acc[0][3]=fmaf(a0.x,wv.w,acc[0][3]);
    acc[1][0]=fmaf(a0.y,wv.x,acc[1][0]); acc[1][1]=fmaf(a0.y,wv.y,acc[1][1]);
    acc[1][2]=fmaf(a0.y,wv.z,acc[1][2]); acc[1][3]=fmaf(a0.y,wv.w,acc[1][3]);
    acc[2][0]=fmaf(a0.z,wv.x,acc[2][0]); acc[2][1]=fmaf(a0.z,wv.y,acc[2][1]);
    acc[2][2]=fmaf(a0.z,wv.z,acc[2][2]); acc[2][3]=fmaf(a0.z,wv.w,acc[2][3]);
    acc[3][0]=fmaf(a0.w,wv.x,acc[3][0]); acc[3][1]=fmaf(a0.w,wv.y,acc[3][1]);
    acc[3][2]=fmaf(a0.w,wv.z,acc[3][2]); acc[3][3]=fmaf(a0.w,wv.w,acc[3][3]);
    acc[4][0]=fmaf(a1.x,wv.x,acc[4][0]); acc[4][1]=fmaf(a1.x,wv.y,acc[4][1]);
    acc[4][2]=fmaf(a1.x,wv.z,acc[4][2]); acc[4][3]=fmaf(a1.x,wv.w,acc[4][3]);
    acc[5][0]=fmaf(a1.y,wv.x,acc[5][0]); acc[5][1]=fmaf(a1.y,wv.y,acc[5][1]);
    acc[5][2]=fmaf(a1.y,wv.z,acc[5][2]); acc[5][3]=fmaf(a1.y,wv.w,acc[5][3]);
    acc[6][0]=fmaf(a1.z,wv.x,acc[6][0]); acc[6][1]=fmaf(a1.z,wv.y,acc[6][1]);
    acc[6][2]=fmaf(a1.z,wv.z,acc[6][2]); acc[6][3]=fmaf(a1.z,wv.w,acc[6][3]);
    acc[7][0]=fmaf(a1.w,wv.x,acc[7][0]); acc[7][1]=fmaf(a1.w,wv.y,acc[7][1]);
    acc[7][2]=fmaf(a1.w,wv.z,acc[7][2]); acc[7][3]=fmaf(a1.w,wv.w,acc[7][3]);
  }
  float* pp = partial + ((size_t)ks*32 + b0)*N + n0;
  #pragma unroll
  for (int bi=0;bi<8;bi++)
    *(float4*)(pp + (size_t)bi*N) =
      make_float4(acc[bi][0],acc[bi][1],acc[bi][2],acc[bi][3]);
}

__global__ __launch_bounds__(256) void k_cell(const float* __restrict__ partial,
    const float* __restrict__ b_ih, const float* __restrict__ b_hh,
    float* __restrict__ c, float* __restrict__ hdst1, float* __restrict__ hdst2){
  int idx = blockIdx.x*256 + threadIdx.x;
  int b = idx >> 10, h = idx & 1023;
  const float* pb = partial + (size_t)b*G4;
  float gi = b_ih[h]      + b_hh[h];
  float gf = b_ih[1024+h] + b_hh[1024+h];
  float gg = b_ih[2048+h] + b_hh[2048+h];
  float go = b_ih[3072+h] + b_hh[3072+h];
  #pragma unroll
  for (int ks=0; ks<16; ks++){
    const float* pp = pb + (size_t)ks*32*G4;
    gi += pp[h]; gf += pp[1024+h]; gg += pp[2048+h]; go += pp[3072+h];
  }
  float cv = c[idx];
  float si = 1.f/(1.f+expf(-gi));
  float sf = 1.f/(1.f+expf(-gf));
  float so = 1.f/(1.f+expf(-go));
  float tg = tanhf(gg);
  float c2 = sf*cv + si*tg;
  float h2 = so*tanhf(c2);
  c[idx] = c2;
  hdst1[h*32 + b] = h2;
  if (hdst2) hdst2[h*32 + b] = h2;
}

__global__ __launch_bounds__(256) void k_predsum(const float* __restrict__ partP,
    const float* __restrict__ b_fc, float* __restrict__ outp,
    float* __restrict__ argv, int* __restrict__ argi, int t){
  int n = blockIdx.x*256 + threadIdx.x;
  int w = threadIdx.x >> 6, lane = threadIdx.x & 63;
  float bias = b_fc[n];
  const float* p0 = partP + n;
  const float* p1 = partP + (size_t)32*NPRED + n;
  for (int b=0;b<32;b++){
    float v = p0[(size_t)b*NPRED] + p1[(size_t)b*NPRED] + bias;
    outp[(size_t)(b*TT + t)*VV + n] = v;
    float bv = v; int bi = n;
    #pragma unroll
    for (int d=32; d>0; d>>=1){
      float ov = __shfl_down(bv, d); int oi = __shfl_down(bi, d);
      if (ov > bv || (ov==bv && oi < bi)){ bv=ov; bi=oi; }
    }
    if (lane==0){
      argv[(blockIdx.x*4 + w)*32 + b] = bv;
      argi[(blockIdx.x*4 + w)*32 + b] = bi;
    }
  }
}

__global__ void k_argfinal(const float* __restrict__ argv,
                           const int* __restrict__ argi,
                           float* __restrict__ predout){
  int b = threadIdx.x >> 3, j = threadIdx.x & 7;
  float bv = -INFINITY; int bi = 0x7fffffff;
  for (int p=j; p<500; p+=8){
    float v = argv[p*32+b]; int ix = argi[p*32+b];
    if (v>bv || (v==bv && ix<bi)){ bv=v; bi=ix; }
  }
  #pragma unroll
  for (int d=4; d>0; d>>=1){
    float ov = __shfl_down(bv, d); int oi = __shfl_down(bi, d);
    if (ov>bv || (ov==bv && oi<bi)){ bv=ov; bi=oi; }
  }
  if (j==0) predout[b*TT + 63] = (float)bi;
}

// =================== persistent cooperative step kernel ===================
struct StepParams {
  const float* ep; const float* encW2; const float* emb;
  const float* W1T; const float* b_in; const float* bad; const float* vatt;
  const float* Wcat0T; const float* Wcat1T; const float* WcatPT;
  const float* b_ih0; const float* b_hh0; const float* b_ih1; const float* b_hh1;
  const float* b_fc;
  float* scores; float* A0T; float* A1T; float* c0; float* c1;
  float* partLS;   // [32][32][4096] (overlays old part0+part1, 16 MB)
  float* partP;    // [4][32][33024] (overlays encT region)
  float* outp; float* predout; float* argv; int* argi; int* token;
};

template<int KSLICE>
__device__ __forceinline__ void gemm_body(const float* __restrict__ AT,
    const float* __restrict__ WT, float* __restrict__ partial,
    int N, int nt, int ks, int w, int lane){
  int n0 = nt*256 + lane*4;
  int b0 = w*8;
  int k0 = ks*KSLICE;
  float acc[8][4];
  #pragma unroll
  for (int i=0;i<8;i++)
    #pragma unroll
    for (int j=0;j<4;j++) acc[i][j]=0.f;
  const float* wp = WT + (size_t)k0*N + n0;
  const float* ap = AT + (size_t)k0*32 + b0;
  #pragma unroll 4
  for (int k=0;k<KSLICE;k++){
    float4 wv = *(const float4*)(wp);
    float4 a0 = *(const float4*)(ap);
    float4 a1 = *(const float4*)(ap+4);
    wp += N; ap += 32;
    acc[0][0]=fmaf(a0.x,wv.x,acc[0][0]); acc[0][1]=fmaf(a0.x,wv.y,acc[0][1]);
    acc[0][2]=fmaf(a0.x,wv.z,acc[0][2]); acc[0][3]=fmaf(a0.x,wv.w,acc[0][3]);
    acc[1][0]=fmaf(a0.y,wv.x,acc[1][0]); acc[1][1]=fmaf(a0.y,wv.y,acc[1][1]);
    acc[1][2]=fmaf(a0.y,wv.z,acc[1][2]); acc[1][3]=fmaf(a0.y,wv.w,acc[1][3]);
    acc[2][0]=fmaf(a0.z,wv.x,acc[2][0]); acc[2][1]=fmaf(a0.z,wv.y,acc[2][1]);
    acc[2][2]=fmaf(a0.z,wv.z,acc[2][2]); acc[2][3]=fmaf(a0.z,wv.w,acc[2][3]);
    acc[3][0]=fmaf(a0.w,wv.x,acc[3][0]); acc[3][1]=fmaf(a0.w,wv.y,acc[3][1]);
    acc[3][2]=fmaf(a0.w,wv.z,acc[3][2]); acc[3][3]=fmaf(a0.w,wv.w,acc[3][3]);
    acc[4][0]=fmaf(a1.x,wv.x,acc[4][0]); acc[4][1]=fmaf(a1.x,wv.y,acc[4][1]);
    acc[4][2]=fmaf(a1.x,wv.z,acc[4][2]); acc[4][3]=fmaf(a1.x,wv.w,acc[4][3]);
    acc[5][0]=fmaf(a1.y,wv.x,acc[5][0]); acc[5][1]=fmaf(a1.y,wv.y,acc[5][1]);
    acc[5][2]=fmaf(a1.y,wv.z,acc[5][2]); acc[5][3]=fmaf(a1.y,wv.w,acc[5][3]);
    acc[6][0]=fmaf(a1.z,wv.x,acc[6][0]); acc[6][1]=fmaf(a1.z,wv.y,acc[6][1]);
    acc[6][2]=fmaf(a1.z,wv.z,acc[6][2]); acc[6][3]=fmaf(a1.z,wv.w,acc[6][3]);
    acc[7][0]=fmaf(a1.w,wv.x,acc[7][0]); acc[7][1]=fmaf(a1.w,wv.y,acc[7][1]);
    acc[7][2]=fmaf(a1.w,wv.z,acc[7][2]); acc[7][3]=fmaf(a1.w,wv.w,acc[7][3]);
  }
  float* pp = partial + ((size_t)ks*32 + b0)*N + n0;
  #pragma unroll
  for (int bi=0;bi<8;bi++)
    *(float4*)(pp + (size_t)bi*N) =
      make_float4(acc[bi][0],acc[bi][1],acc[bi][2],acc[bi][3]);
}

__device__ __forceinline__ void cell_body(const float* __restrict__ partial,
    const float* __restrict__ b_ih, const float* __restrict__ b_hh,
    float* __restrict__ c, float* __restrict__ hdst1, float* __restrict__ hdst2,
    int idx){
  int b = idx >> 10, h = idx & 1023;
  const float* pb = partial + (size_t)b*G4;
  float gi = b_ih[h]      + b_hh[h];
  float gf = b_ih[1024+h] + b_hh[1024+h];
  float gg = b_ih[2048+h] + b_hh[2048+h];
  float go = b_ih[3072+h] + b_hh[3072+h];
  #pragma unroll 8
  for (int ks=0; ks<32; ks++){
    const float* pp = pb + (size_t)ks*32*G4;
    gi += pp[h]; gf += pp[1024+h]; gg += pp[2048+h]; go += pp[3072+h];
  }
  float cv = c[idx];
  float si = 1.f/(1.f+expf(-gi));
  float sf = 1.f/(1.f+expf(-gf));
  float so = 1.f/(1.f+expf(-go));
  float tg = tanhf(gg);
  float c2 = sf*cv + si*tg;
  float h2 = so*tanhf(c2);
  c[idx] = c2;
  hdst1[h*32 + b] = h2;
  if (hdst2) hdst2[h*32 + b] = h2;
}

__global__ __launch_bounds__(256, 3) void k_steps(StepParams P){
  cg::grid_group grid = cg::this_grid();
  const int vbid = blockIdx.x;
  const int tx = threadIdx.x;
  const int w = tx >> 6, lane = tx & 63;
  __shared__ __align__(16) float smem[2048];

  for (int t=1; t<TT; t++){
    // ---- phase 1: attention scores + prev-step argmax ----
    if (vbid < 512){
      int b = vbid & 31, lt = vbid >> 5;
      float* qs = smem; float* vs = smem + 1024;
      for (int i=tx; i<HH; i+=256){
        float qv = P.bad[i];
        if (t > 1){
          qv += P.partP[(size_t)b*NPRED + VV + i]
              + P.partP[(size_t)(32+b)*NPRED + VV + i]
              + P.partP[(size_t)(64+b)*NPRED + VV + i]
              + P.partP[(size_t)(96+b)*NPRED + VV + i];
        }
        qs[i] = qv;
        vs[i] = P.vatt[i];
      }
      __syncthreads();
      if (lt==0 && t>1 && w==0){
        float bv = -INFINITY; int bi = 0x7fffffff;
        for (int j=lane; j<500; j+=64){
          float v = P.argv[j*32 + b]; int ix = P.argi[j*32 + b];
          if (v > bv || (v==bv && ix < bi)){ bv=v; bi=ix; }
        }
        #pragma unroll
        for (int d=32; d>0; d>>=1){
          float ov = __shfl_down(bv, d); int oi = __shfl_down(bi, d);
          if (ov > bv || (ov==bv && oi < bi)){ bv=ov; bi=oi; }
        }
        if (lane==0){ P.token[b]=bi; P.predout[b*TT + (t-1)] = (float)bi; }
      }
      #pragma unroll
      for (int i=0;i<8;i++){
        int l = lt*32 + w*8 + i;
        const float4* row = (const float4*)(P.ep + ((size_t)(b*LL + l))*HH);
        float acc = 0.f;
        #pragma unroll
        for (int c=0;c<4;c++){
          float4 xv = row[c*64 + lane];
          float4 qv = ((const float4*)qs)[c*64 + lane];
          float4 vv = ((const float4*)vs)[c*64 + lane];
          acc += fast_tanh(xv.x+qv.x)*vv.x;
          acc += fast_tanh(xv.y+qv.y)*vv.y;
          acc += fast_tanh(xv.z+qv.z)*vv.z;
          acc += fast_tanh(xv.w+qv.w)*vv.w;
        }
        #pragma unroll
        for (int d=32; d>0; d>>=1) acc += __shfl_down(acc, d);
        if (lane==0) P.scores[b*LL + l] = acc;
      }
    }
    grid.sync();
    // ---- phase 2: softmax + x = [emb,ctx]@W_in^T + b_in ----
    if (vbid < 256){
      int b = vbid & 31, et = vbid >> 5;
      float* alpha = smem;           // 512
      float* embs  = smem + 512;     // 512
      float* red   = smem + 1024;    // 8
      float* comb  = smem + 1040;    // 4*64
      float s0 = P.scores[b*LL + tx], s1 = P.scores[b*LL + 256 + tx];
      float mx = fmaxf(s0, s1);
      #pragma unroll
      for (int d=32; d>0; d>>=1) mx = fmaxf(mx, __shfl_down(mx, d));
      if ((tx&63)==0) red[tx>>6] = mx;
      __syncthreads();
      mx = fmaxf(fmaxf(red[0],red[1]), fmaxf(red[2],red[3]));
      float e0 = __expf(s0-mx), e1 = __expf(s1-mx);
      float ssum = e0+e1;
      #pragma unroll
      for (int d=32; d>0; d>>=1) ssum += __shfl_down(ssum, d);
      if ((tx&63)==0) red[4+(tx>>6)] = ssum;
      __syncthreads();
      ssum = red[4]+red[5]+red[6]+red[7];
      float inv = 1.0f/ssum;
      alpha[tx] = e0*inv; alpha[tx+256] = e1*inv;
      int tok = P.token[b];
      embs[tx] = P.emb[(size_t)tok*EE + tx];
      embs[tx+256] = P.emb[(size_t)tok*EE + 256 + tx];
      __syncthreads();
      int e = et*64 + lane;
      float acc = 0.f;
      const float* cw = P.encW2 + (size_t)b*LL*EE + (size_t)w*128*EE + e;
      #pragma unroll 4
      for (int l=0;l<128;l++) acc = fmaf(alpha[w*128+l], cw[(size_t)l*EE], acc);
      const float* wpp = P.W1T + (size_t)w*128*EE + e;
      #pragma unroll 4
      for (int j=0;j<128;j++) acc = fmaf(embs[w*128+j], wpp[(size_t)j*EE], acc);
      comb[w*64 + lane] = acc;
      __syncthreads();
      if (w==0){
        float r = comb[lane]+comb[64+lane]+comb[128+lane]+comb[192+lane] + P.b_in[e];
        P.A0T[e*32 + b] = r;
      }
    }
    grid.sync();
    // ---- phase 3: LSTM0 gates GEMM (32-way split-K, 512 blocks) ----
    if (vbid < 512)
      gemm_body<48>(P.A0T, P.Wcat0T, P.partLS, G4, vbid & 15, vbid >> 4, w, lane);
    grid.sync();
    // ---- phase 4: LSTM0 cell ----
    if (vbid < 128)
      cell_body(P.partLS, P.b_ih0, P.b_hh0, P.c0,
                P.A0T + (size_t)512*32, P.A1T, vbid*256 + tx);
    grid.sync();
    // ---- phase 5: LSTM1 gates GEMM ----
    if (vbid < 512)
      gemm_body<64>(P.A1T, P.Wcat1T, P.partLS, G4, vbid & 15, vbid >> 4, w, lane);
    grid.sync();
    // ---- phase 6: LSTM1 cell ----
    if (vbid < 128)
      cell_body(P.partLS, P.b_ih1, P.b_hh1, P.c1,
                P.A1T + (size_t)1024*32, nullptr, vbid*256 + tx);
    grid.sync();
    // ---- phase 7: fused [W_fc ; W_att_dec] GEMM (4-way split-K, 516 blocks) ----
    {
      int nt = vbid % 129, ks = vbid / 129;
      gemm_body<256>(P.A1T + (size_t)1024*32, P.WcatPT, P.partP, NPRED,
                     nt, ks, w, lane);
    }
    grid.sync();
    // ---- phase 8: logits = sum partials + bias; write out; argmax partials --
    if (vbid < 125){
      int n = vbid*256 + tx;
      float bias = P.b_fc[n];
      const float* p0 = P.partP + n;
      const float* p1 = P.partP + (size_t)32*NPRED + n;
      const float* p2 = P.partP + (size_t)64*NPRED + n;
      const float* p3 = P.partP + (size_t)96*NPRED + n;
      for (int b=0;b<32;b++){
        float v = p0[(size_t)b*NPRED] + p1[(size_t)b*NPRED]
                + p2[(size_t)b*NPRED] + p3[(size_t)b*NPRED] + bias;
        P.outp[(size_t)(b*TT + t)*VV + n] = v;
        float bv = v; int bi = n;
        #pragma unroll
        for (int d=32; d>0; d>>=1){
          float ov = __shfl_down(bv, d); int oi = __shfl_down(bi, d);
          if (ov > bv || (ov==bv && oi < bi)){ bv=ov; bi=oi; }
        }
        if (lane==0){
          P.argv[(vbid*4 + w)*32 + b] = bv;
          P.argi[(vbid*4 + w)*32 + b] = bi;
        }
      }
    }
    grid.sync();
  }
  // ---- final argmax (t=63) ----
  if (vbid == 0){
    int b = tx >> 3, j = tx & 7;
    float bv = -INFINITY; int bi = 0x7fffffff;
    for (int p=j; p<500; p+=8){
      float v = P.argv[p*32+b]; int ix = P.argi[p*32+b];
      if (v>bv || (v==bv && ix<bi)){ bv=v; bi=ix; }
    }
    #pragma unroll
    for (int d=4; d>0; d>>=1){
      float ov = __shfl_down(bv, d); int oi = __shfl_down(bi, d);
      if (ov>bv || (ov==bv && oi<bi)){ bv=ov; bi=oi; }
    }
    if (j==0) P.predout[b*TT + 63] = (float)bi;
  }
}

extern "C" void kernel_launch(void* const* d_in, const int* in_sizes, int n_in,
                              void* d_out, int out_size, void* d_ws, size_t ws_size,
                              hipStream_t stream){
  const float* enc_output=(const float*)d_in[0];
  const int*   trg       =(const int*)d_in[1];
  const float* emb       =(const float*)d_in[2];
  const float* W_att_enc =(const float*)d_in[3];
  const float* b_att_enc =(const float*)d_in[4];
  const float* W_att_dec =(const float*)d_in[5];
  const float* b_att_dec =(const float*)d_in[6];
  const float* v_att     =(const float*)d_in[7];
  const float* W_in      =(const float*)d_in[8];
  const float* b_in      =(const float*)d_in[9];
  const float* W_ih0     =(const float*)d_in[10];
  const float* W_hh0     =(const float*)d_in[11];
  const float* b_ih0     =(const float*)d_in[12];
  const float* b_hh0     =(const float*)d_in[13];
  const float* W_ih1     =(const float*)d_in[14];
  const float* W_hh1     =(const float*)d_in[15];
  const float* b_ih1     =(const float*)d_in[16];
  const float* b_hh1     =(const float*)d_in[17];
  const float* W_fc      =(const float*)d_in[18];
  const float* b_fc      =(const float*)d_in[19];
  const int*   sosp      =(const int*)d_in[23];

  float* out = (float*)d_out;
  float* predout = out + (size_t)BB*TT*VV;
  float* ws = (float*)d_ws;

  float* WcatPT = ws;                      // [1024][33024]
  float* Wcat0T = ws + 33816576;           // [1536][4096]
  float* Wcat1T = ws + 40108032;           // [2048][4096]
  float* W1T    = ws + 48496640;           // [512][512]
  float* WinCtxT= ws + 48758784;           // [1024][512]
  float* WattET = ws + 49283072;           // [1024][1024]
  float* encT   = ws + 50331648;           // [1024][16384] (precompute only)
  float* partP  = encT;                    // [4][32][33024] reuses encT region
  float* ep     = ws + 67108864;           // [16384][1024]
  float* encW2  = ws + 83886080;           // [16384][512]
  float* part0  = ws + 92274688;           // old [16][32][4096]
  float* part1  = ws + 94371840;           // old [16][32][4096]
  float* partLS = part0;                   // new [32][32][4096] spans part0+part1
  float* A0T    = ws + 96468992;           // [1536][32]  = [x ; h0]
  float* A1T    = ws + 96518144;           // [2048][32]  = [h0 ; h1]
  float* c0     = ws + 96583680;
  float* c1     = ws + 96616448;
  float* q      = ws + 96649216;           // legacy (unused in steps)
  float* scores = ws + 96681984;           // [32][512]
  float* argv   = ws + 96698368;           // [500][32]
  int*   argi   = (int*)(ws + 96714368);   // [500][32]
  int*   token  = (int*)(ws + 96730368);   // [32]

  k_init<<<dim3(4833), dim3(256), 0, stream>>>(out, A0T, A1T, c0, c1, q,
      b_att_dec, token, trg, sosp, predout);

  auto TR=[&](const float* src,int ss,float* dst,int ds,int R,int C){
    k_transpose<<<dim3(C/32, R/32), dim3(32,8), 0, stream>>>(src, ss, dst, ds, R, C);
  };
  TR(W_fc, 1024, WcatPT, NPRED, VV, 1024);
  TR(W_att_dec, 1024, WcatPT + VV, NPRED, 1024, 1024);
  TR(W_ih0, 512, Wcat0T, G4, G4, 512);
  TR(W_hh0, 1024, Wcat0T + (size_t)512*G4, G4, G4, 1024);
  TR(W_ih1, 1024, Wcat1T, G4, G4, 1024);
  TR(W_hh1, 1024, Wcat1T + (size_t)1024*G4, G4, G4, 1024);
  TR(W_in, 1536, W1T, 512, 512, 512);
  TR(W_in + 512, 1536, WinCtxT, 512, 512, 1024);
  TR(W_att_enc, 1024, WattET, 1024, 1024, 1024);
  TR(enc_output, 1024, encT, 16384, 16384, 1024);

  k_pregemm<<<dim3(256,8), dim3(256), 0, stream>>>(encT, WattET, b_att_enc, ep, 1024, 1024);
  k_pregemm<<<dim3(256,4), dim3(256), 0, stream>>>(encT, WinCtxT, nullptr, encW2, 512, 1024);

  StepParams P;
  P.ep = ep; P.encW2 = encW2; P.emb = emb;
  P.W1T = W1T; P.b_in = b_in; P.bad = b_att_dec; P.vatt = v_att;
  P.Wcat0T = Wcat0T; P.Wcat1T = Wcat1T; P.WcatPT = WcatPT;
  P.b_ih0 = b_ih0; P.b_hh0 = b_hh0; P.b_ih1 = b_ih1; P.b_hh1 = b_hh1;
  P.b_fc = b_fc;
  P.scores = scores; P.A0T = A0T; P.A1T = A1T; P.c0 = c0; P.c1 = c1;
  P.partLS = partLS; P.partP = partP;
  P.outp = out; P.predout = predout; P.argv = argv; P.argi = argi; P.token = token;

  void* kargs[] = { (void*)&P };
  hipError_t err = hipLaunchCooperativeKernel((const void*)k_steps,
      dim3(NBLK), dim3(256), kargs, 0, stream);

  if (err != hipSuccess){
    (void)hipGetLastError();  // clear error state; run legacy per-step path
    for (int t=1; t<TT; t++){
      k_score<<<dim3(32,16), dim3(256), 0, stream>>>(ep, partP, b_att_dec, v_att,
          scores, argv, argi, token, predout, t);
      k_attnx<<<dim3(32,8), dim3(256), 0, stream>>>(scores, encW2, emb, token,
          W1T, b_in, A0T);
      k_gemm_smallM<<<dim3(16,16), dim3(256), 0, stream>>>(A0T, Wcat0T, part0,
          G4, 96);
      k_cell<<<dim3(128), dim3(256), 0, stream>>>(part0, b_ih0, b_hh0, c0,
          A0T + (size_t)512*32, A1T);
      k_gemm_smallM<<<dim3(16,16), dim3(256), 0, stream>>>(A1T, Wcat1T, part1,
          G4, 128);
      k_cell<<<dim3(128), dim3(256), 0, stream>>>(part1, b_ih1, b_hh1, c1,
          A1T + (size_t)1024*32, nullptr);
      k_gemm_smallM<<<dim3(129,2), dim3(256), 0, stream>>>(A1T + (size_t)1024*32,
          WcatPT, partP, NPRED, 512);
      k_predsum<<<dim3(125), dim3(256), 0, stream>>>(partP, b_fc, out, argv, argi, t);
    }
    k_argfinal<<<dim3(1), dim3(256), 0, stream>>>(argv, argi, predout);
  }
}

// Round 3
// 17061.618 us; speedup vs baseline: 3.1129x; 3.1129x over previous
//
#include <hip/hip_runtime.h>
#include <math.h>

#define BB 32
#define LL 512
#define EE 512
#define HH 1024
#define VV 32000
#define TT 64
#define G4 4096
#define NPRED 33024  // VV + HH

__device__ __forceinline__ float fast_tanh(float x){
  float ax = fabsf(x);
  float e = __expf(ax + ax);
  float r = 1.0f - 2.0f/(e + 1.0f);
  return copysignf(r, x);
}

// ---------------- init ----------------
__global__ void k_init(float* __restrict__ outp, float* __restrict__ a0t,
                       float* __restrict__ a1t, float* __restrict__ c0,
                       float* __restrict__ c1, float* __restrict__ q,
                       const float* __restrict__ bad, int* __restrict__ token,
                       const int* __restrict__ trg, const int* __restrict__ sosp,
                       float* __restrict__ predout){
  int idx = blockIdx.x*256 + threadIdx.x;
  if (idx < 1024000){ int b = idx / VV; int v = idx % VV;
    outp[(size_t)b*TT*VV + v] = 0.f; return; }
  idx -= 1024000;
  if (idx < 49152){ a0t[idx]=0.f; return; } idx -= 49152;
  if (idx < 65536){ a1t[idx]=0.f; return; } idx -= 65536;
  if (idx < 32768){ c0[idx]=0.f; return; } idx -= 32768;
  if (idx < 32768){ c1[idx]=0.f; return; } idx -= 32768;
  if (idx < 32768){ q[idx] = bad[idx & (HH-1)]; return; } idx -= 32768;
  if (idx < 32){ token[idx] = trg[idx*TT]; return; } idx -= 32;
  if (idx < 32){ predout[idx*TT] = (float)(*sosp); return; }
}

// ---------------- generic transpose: dst[c*ds + r] = src[r*ss + c] ----------
__global__ void k_transpose(const float* __restrict__ src, int ss,
                            float* __restrict__ dst, int ds, int R, int C){
  __shared__ float tile[32][33];
  int c0 = blockIdx.x*32, r0 = blockIdx.y*32;
  int tx = threadIdx.x, ty = threadIdx.y;  // (32,8)
  #pragma unroll
  for (int i=0;i<32;i+=8)
    tile[ty+i][tx] = src[(size_t)(r0+ty+i)*ss + c0+tx];
  __syncthreads();
  #pragma unroll
  for (int i=0;i<32;i+=8)
    dst[(size_t)(c0+ty+i)*ds + r0+tx] = tile[tx][ty+i];
}

// ---------------- precompute GEMM: C[m][n] = sum_k AT[k][m]*WT[k][n] (+bias)
__global__ __launch_bounds__(256) void k_pregemm(const float* __restrict__ AT,
    const float* __restrict__ WT, const float* __restrict__ bias,
    float* __restrict__ Cout, int N, int Kdim){
  int mt = blockIdx.x, ntg = blockIdx.y;
  int w = threadIdx.x >> 6, lane = threadIdx.x & 63;
  int m = mt*64 + lane;
  int nbase = ntg*128 + w*32;
  float acc[32];
  #pragma unroll
  for (int j=0;j<32;j++) acc[j]=0.f;
  const float* ap = AT + m;
  const float* wp = WT + nbase;
  for (int k=0;k<Kdim;k++){
    float a = ap[(size_t)k*16384];
    const float4* w4 = (const float4*)(wp + (size_t)k*N);
    #pragma unroll
    for (int j4=0;j4<8;j4++){
      float4 wv = w4[j4];
      acc[j4*4+0] = fmaf(a, wv.x, acc[j4*4+0]);
      acc[j4*4+1] = fmaf(a, wv.y, acc[j4*4+1]);
      acc[j4*4+2] = fmaf(a, wv.z, acc[j4*4+2]);
      acc[j4*4+3] = fmaf(a, wv.w, acc[j4*4+3]);
    }
  }
  __shared__ float tile[64][133];
  #pragma unroll
  for (int j=0;j<32;j++){
    float bv = bias ? bias[nbase+j] : 0.f;
    tile[lane][w*32+j] = acc[j] + bv;
  }
  __syncthreads();
  #pragma unroll
  for (int i=0;i<32;i++){
    int flat = i*256 + threadIdx.x;
    int mm = flat >> 7, nn = flat & 127;
    Cout[(size_t)(mt*64+mm)*N + ntg*128 + nn] = tile[mm][nn];
  }
}

// ---------------- attention scores + q-combine + argmax of prev pred --------
// grid (32 b, 16 lt), block 256 (4 waves x 8 l each = 32 l per block)
__global__ __launch_bounds__(256) void k_score(const float* __restrict__ ep,
    const float* __restrict__ partP, const float* __restrict__ bad,
    const float* __restrict__ vatt, float* __restrict__ scores,
    const float* __restrict__ argv, const int* __restrict__ argi,
    int* __restrict__ token, float* __restrict__ predout, int t){
  int b = blockIdx.x, lt = blockIdx.y;
  int w = threadIdx.x >> 6, lane = threadIdx.x & 63;
  __shared__ float qs[HH], vs[HH];
  for (int i=threadIdx.x; i<HH; i+=256){
    float qv = bad[i];
    if (t > 1){
      qv += partP[(size_t)b*NPRED + VV + i]
          + partP[(size_t)(32+b)*NPRED + VV + i]
          + partP[(size_t)(64+b)*NPRED + VV + i]
          + partP[(size_t)(96+b)*NPRED + VV + i];
    }
    qs[i] = qv;
    vs[i] = vatt[i];
  }
  __syncthreads();
  if (lt==0 && t>1 && w==0){
    float bv = -INFINITY; int bi = 0x7fffffff;
    for (int j=lane; j<500; j+=64){
      float v = argv[j*32 + b]; int ix = argi[j*32 + b];
      if (v > bv || (v==bv && ix < bi)){ bv=v; bi=ix; }
    }
    #pragma unroll
    for (int d=32; d>0; d>>=1){
      float ov = __shfl_down(bv, d); int oi = __shfl_down(bi, d);
      if (ov > bv || (ov==bv && oi < bi)){ bv=ov; bi=oi; }
    }
    if (lane==0){ token[b]=bi; predout[b*TT + (t-1)] = (float)bi; }
  }
  #pragma unroll
  for (int i=0;i<8;i++){
    int l = lt*32 + w*8 + i;
    const float4* row = (const float4*)(ep + ((size_t)(b*LL + l))*HH);
    float acc = 0.f;
    #pragma unroll
    for (int c=0;c<4;c++){
      float4 xv = row[c*64 + lane];
      float4 qv = ((const float4*)qs)[c*64 + lane];
      float4 vv = ((const float4*)vs)[c*64 + lane];
      acc += fast_tanh(xv.x+qv.x)*vv.x;
      acc += fast_tanh(xv.y+qv.y)*vv.y;
      acc += fast_tanh(xv.z+qv.z)*vv.z;
      acc += fast_tanh(xv.w+qv.w)*vv.w;
    }
    #pragma unroll
    for (int d=32; d>0; d>>=1) acc += __shfl_down(acc, d);
    if (lane==0) scores[b*LL + l] = acc;
  }
}

// ---------------- softmax + x = alpha@encW2 + emb@W1T + b_in ----------------
__global__ __launch_bounds__(256) void k_attnx(const float* __restrict__ scores,
    const float* __restrict__ encW2, const float* __restrict__ emb,
    const int* __restrict__ token, const float* __restrict__ W1T,
    const float* __restrict__ b_in, float* __restrict__ A0T){
  int b = blockIdx.x, et = blockIdx.y;
  int tx = threadIdx.x;
  int w = tx >> 6, lane = tx & 63;
  __shared__ float alpha[LL];
  __shared__ float embs[EE];
  __shared__ float red[8];
  __shared__ float comb[4][64];
  float s0 = scores[b*LL + tx], s1 = scores[b*LL + 256 + tx];
  float mx = fmaxf(s0, s1);
  #pragma unroll
  for (int d=32; d>0; d>>=1) mx = fmaxf(mx, __shfl_down(mx, d));
  if ((tx&63)==0) red[tx>>6] = mx;
  __syncthreads();
  mx = fmaxf(fmaxf(red[0],red[1]), fmaxf(red[2],red[3]));
  float e0 = __expf(s0-mx), e1 = __expf(s1-mx);
  float sm = e0+e1;
  #pragma unroll
  for (int d=32; d>0; d>>=1) sm += __shfl_down(sm, d);
  if ((tx&63)==0) red[4+(tx>>6)] = sm;
  __syncthreads();
  sm = red[4]+red[5]+red[6]+red[7];
  float inv = 1.0f/sm;
  alpha[tx] = e0*inv; alpha[tx+256] = e1*inv;
  int tok = token[b];
  embs[tx] = emb[(size_t)tok*EE + tx];
  embs[tx+256] = emb[(size_t)tok*EE + 256 + tx];
  __syncthreads();
  int e = et*64 + lane;
  float acc = 0.f;
  const float* cw = encW2 + (size_t)b*LL*EE + (size_t)w*128*EE + e;
  #pragma unroll 4
  for (int l=0;l<128;l++) acc = fmaf(alpha[w*128+l], cw[(size_t)l*EE], acc);
  const float* wp = W1T + (size_t)w*128*EE + e;
  #pragma unroll 4
  for (int j=0;j<128;j++) acc = fmaf(embs[w*128+j], wp[(size_t)j*EE], acc);
  comb[w][lane] = acc;
  __syncthreads();
  if (w==0){
    float r = comb[0][lane]+comb[1][lane]+comb[2][lane]+comb[3][lane] + b_in[e];
    A0T[e*32 + b] = r;
  }
}

// ---------------- small-M GEMM v2: LDS-staged A, pipelined W stream ---------
// partial[ks][b][n] = sum_{k in slice} A[k][b] * W[k][n]
// A layout [K][32]; W layout [K][N]. block 256 = 4 waves; wave w -> b in [8w,8w+8)
// lane covers 4 consecutive n; block covers 256 n. grid (N/256, ksplit).
template<int KSLICE>
__global__ __launch_bounds__(256) void k_gemm2(const float* __restrict__ AT,
    const float* __restrict__ WT, float* __restrict__ partial, int N){
  __shared__ __align__(16) float As[KSLICE*32];
  int nt = blockIdx.x, ks = blockIdx.y;
  int w = threadIdx.x >> 6, lane = threadIdx.x & 63;
  int k0 = ks*KSLICE;
  // cooperative coalesced stage of A[k0:k0+KSLICE][0:32] into LDS
  const float4* asrc = (const float4*)(AT + (size_t)k0*32);
  #pragma unroll
  for (int i=threadIdx.x; i<KSLICE*8; i+=256)
    ((float4*)As)[i] = asrc[i];
  __syncthreads();
  int n0 = nt*256 + lane*4;
  int b0 = w*8;
  float acc[8][4];
  #pragma unroll
  for (int i=0;i<8;i++)
    #pragma unroll
    for (int j=0;j<4;j++) acc[i][j]=0.f;
  const float* wp = WT + (size_t)k0*N + n0;
  const float* ap = As + b0;              // wave-uniform -> LDS broadcast reads
  float4 wv = *(const float4*)wp; wp += N;  // depth-2 prefetch
  #pragma unroll 4
  for (int k=0;k<KSLICE-1;k++){
    float4 wn = *(const float4*)wp; wp += N;
    float4 a0 = *(const float4*)(ap);
    float4 a1 = *(const float4*)(ap+4);
    ap += 32;
    acc[0][0]=fmaf(a0.x,wv.x,acc[0][0]); acc[0][1]=fmaf(a0.x,wv.y,acc[0][1]);
    acc[0][2]=fmaf(a0.x,wv.z,acc[0][2]); acc[0][3]=fmaf(a0.x,wv.w,acc[0][3]);
    acc[1][0]=fmaf(a0.y,wv.x,acc[1][0]); acc[1][1]=fmaf(a0.y,wv.y,acc[1][1]);
    acc[1][2]=fmaf(a0.y,wv.z,acc[1][2]); acc[1][3]=fmaf(a0.y,wv.w,acc[1][3]);
    acc[2][0]=fmaf(a0.z,wv.x,acc[2][0]); acc[2][1]=fmaf(a0.z,wv.y,acc[2][1]);
    acc[2][2]=fmaf(a0.z,wv.z,acc[2][2]); acc[2][3]=fmaf(a0.z,wv.w,acc[2][3]);
    acc[3][0]=fmaf(a0.w,wv.x,acc[3][0]); acc[3][1]=fmaf(a0.w,wv.y,acc[3][1]);
    acc[3][2]=fmaf(a0.w,wv.z,acc[3][2]); acc[3][3]=fmaf(a0.w,wv.w,acc[3][3]);
    acc[4][0]=fmaf(a1.x,wv.x,acc[4][0]); acc[4][1]=fmaf(a1.x,wv.y,acc[4][1]);
    acc[4][2]=fmaf(a1.x,wv.z,acc[4][2]); acc[4][3]=fmaf(a1.x,wv.w,acc[4][3]);
    acc[5][0]=fmaf(a1.y,wv.x,acc[5][0]); acc[5][1]=fmaf(a1.y,wv.y,acc[5][1]);
    acc[5][2]=fmaf(a1.y,wv.z,acc[5][2]); acc[5][3]=fmaf(a1.y,wv.w,acc[5][3]);
    acc[6][0]=fmaf(a1.z,wv.x,acc[6][0]); acc[6][1]=fmaf(a1.z,wv.y,acc[6][1]);
    acc[6][2]=fmaf(a1.z,wv.z,acc[6][2]); acc[6][3]=fmaf(a1.z,wv.w,acc[6][3]);
    acc[7][0]=fmaf(a1.w,wv.x,acc[7][0]); acc[7][1]=fmaf(a1.w,wv.y,acc[7][1]);
    acc[7][2]=fmaf(a1.w,wv.z,acc[7][2]); acc[7][3]=fmaf(a1.w,wv.w,acc[7][3]);
    wv = wn;
  }
  {
    float4 a0 = *(const float4*)(ap);
    float4 a1 = *(const float4*)(ap+4);
    acc[0][0]=fmaf(a0.x,wv.x,acc[0][0]); acc[0][1]=fmaf(a0.x,wv.y,acc[0][1]);
    acc[0][2]=fmaf(a0.x,wv.z,acc[0][2]); acc[0][3]=fmaf(a0.x,wv.w,acc[0][3]);
    acc[1][0]=fmaf(a0.y,wv.x,acc[1][0]); acc[1][1]=fmaf(a0.y,wv.y,acc[1][1]);
    acc[1][2]=fmaf(a0.y,wv.z,acc[1][2]); acc[1][3]=fmaf(a0.y,wv.w,acc[1][3]);
    acc[2][0]=fmaf(a0.z,wv.x,acc[2][0]); acc[2][1]=fmaf(a0.z,wv.y,acc[2][1]);
    acc[2][2]=fmaf(a0.z,wv.z,acc[2][2]); acc[2][3]=fmaf(a0.z,wv.w,acc[2][3]);
    acc[3][0]=fmaf(a0.w,wv.x,acc[3][0]); acc[3][1]=fmaf(a0.w,wv.y,acc[3][1]);
    acc[3][2]=fmaf(a0.w,wv.z,acc[3][2]); acc[3][3]=fmaf(a0.w,wv.w,acc[3][3]);
    acc[4][0]=fmaf(a1.x,wv.x,acc[4][0]); acc[4][1]=fmaf(a1.x,wv.y,acc[4][1]);
    acc[4][2]=fmaf(a1.x,wv.z,acc[4][2]); acc[4][3]=fmaf(a1.x,wv.w,acc[4][3]);
    acc[5][0]=fmaf(a1.y,wv.x,acc[5][0]); acc[5][1]=fmaf(a1.y,wv.y,acc[5][1]);
    acc[5][2]=fmaf(a1.y,wv.z,acc[5][2]); acc[5][3]=fmaf(a1.y,wv.w,acc[5][3]);
    acc[6][0]=fmaf(a1.z,wv.x,acc[6][0]); acc[6][1]=fmaf(a1.z,wv.y,acc[6][1]);
    acc[6][2]=fmaf(a1.z,wv.z,acc[6][2]); acc[6][3]=fmaf(a1.z,wv.w,acc[6][3]);
    acc[7][0]=fmaf(a1.w,wv.x,acc[7][0]); acc[7][1]=fmaf(a1.w,wv.y,acc[7][1]);
    acc[7][2]=fmaf(a1.w,wv.z,acc[7][2]); acc[7][3]=fmaf(a1.w,wv.w,acc[7][3]);
  }
  float* pp = partial + ((size_t)ks*32 + b0)*N + n0;
  #pragma unroll
  for (int bi=0;bi<8;bi++)
    *(float4*)(pp + (size_t)bi*N) =
      make_float4(acc[bi][0],acc[bi][1],acc[bi][2],acc[bi][3]);
}

// ---------------- cell update (reduces 16 K-split partials) -----------------
// grid 256 x 128 threads: spread across all CUs
__global__ __launch_bounds__(128) void k_cell(const float* __restrict__ partial,
    const float* __restrict__ b_ih, const float* __restrict__ b_hh,
    float* __restrict__ c, float* __restrict__ hdst1, float* __restrict__ hdst2){
  int idx = blockIdx.x*128 + threadIdx.x;
  int b = idx >> 10, h = idx & 1023;
  const float* pb = partial + (size_t)b*G4;
  float gi = b_ih[h]      + b_hh[h];
  float gf = b_ih[1024+h] + b_hh[1024+h];
  float gg = b_ih[2048+h] + b_hh[2048+h];
  float go = b_ih[3072+h] + b_hh[3072+h];
  #pragma unroll
  for (int ks=0; ks<16; ks++){
    const float* pp = pb + (size_t)ks*32*G4;
    gi += pp[h]; gf += pp[1024+h]; gg += pp[2048+h]; go += pp[3072+h];
  }
  float cv = c[idx];
  float si = 1.f/(1.f+expf(-gi));
  float sf = 1.f/(1.f+expf(-gf));
  float so = 1.f/(1.f+expf(-go));
  float tg = tanhf(gg);
  float c2 = sf*cv + si*tg;
  float h2 = so*tanhf(c2);
  c[idx] = c2;
  hdst1[h*32 + b] = h2;
  if (hdst2) hdst2[h*32 + b] = h2;
}

// ---------------- combine pred partials + bias, write logits, argmax --------
// grid (250), block 128: n = blk*128+tx in [0,32000); argv rows = blk*2+w (500)
__global__ __launch_bounds__(128) void k_predsum(const float* __restrict__ partP,
    const float* __restrict__ b_fc, float* __restrict__ outp,
    float* __restrict__ argv, int* __restrict__ argi, int t){
  int n = blockIdx.x*128 + threadIdx.x;
  int w = threadIdx.x >> 6, lane = threadIdx.x & 63;
  float bias = b_fc[n];
  const float* p0 = partP + n;
  const float* p1 = partP + (size_t)32*NPRED + n;
  const float* p2 = partP + (size_t)64*NPRED + n;
  const float* p3 = partP + (size_t)96*NPRED + n;
  for (int b=0;b<32;b++){
    float v = p0[(size_t)b*NPRED] + p1[(size_t)b*NPRED]
            + p2[(size_t)b*NPRED] + p3[(size_t)b*NPRED] + bias;
    outp[(size_t)(b*TT + t)*VV + n] = v;
    float bv = v; int bi = n;
    #pragma unroll
    for (int d=32; d>0; d>>=1){
      float ov = __shfl_down(bv, d); int oi = __shfl_down(bi, d);
      if (ov > bv || (ov==bv && oi < bi)){ bv=ov; bi=oi; }
    }
    if (lane==0){
      argv[(blockIdx.x*2 + w)*32 + b] = bv;
      argi[(blockIdx.x*2 + w)*32 + b] = bi;
    }
  }
}

// ---------------- final argmax (step 63) ----------------
__global__ void k_argfinal(const float* __restrict__ argv,
                           const int* __restrict__ argi,
                           float* __restrict__ predout){
  int b = threadIdx.x >> 3, j = threadIdx.x & 7;
  float bv = -INFINITY; int bi = 0x7fffffff;
  for (int p=j; p<500; p+=8){
    float v = argv[p*32+b]; int ix = argi[p*32+b];
    if (v>bv || (v==bv && ix<bi)){ bv=v; bi=ix; }
  }
  #pragma unroll
  for (int d=4; d>0; d>>=1){
    float ov = __shfl_down(bv, d); int oi = __shfl_down(bi, d);
    if (ov>bv || (ov==bv && oi<bi)){ bv=ov; bi=oi; }
  }
  if (j==0) predout[b*TT + 63] = (float)bi;
}

extern "C" void kernel_launch(void* const* d_in, const int* in_sizes, int n_in,
                              void* d_out, int out_size, void* d_ws, size_t ws_size,
                              hipStream_t stream){
  const float* enc_output=(const float*)d_in[0];
  const int*   trg       =(const int*)d_in[1];
  const float* emb       =(const float*)d_in[2];
  const float* W_att_enc =(const float*)d_in[3];
  const float* b_att_enc =(const float*)d_in[4];
  const float* W_att_dec =(const float*)d_in[5];
  const float* b_att_dec =(const float*)d_in[6];
  const float* v_att     =(const float*)d_in[7];
  const float* W_in      =(const float*)d_in[8];
  const float* b_in      =(const float*)d_in[9];
  const float* W_ih0     =(const float*)d_in[10];
  const float* W_hh0     =(const float*)d_in[11];
  const float* b_ih0     =(const float*)d_in[12];
  const float* b_hh0     =(const float*)d_in[13];
  const float* W_ih1     =(const float*)d_in[14];
  const float* W_hh1     =(const float*)d_in[15];
  const float* b_ih1     =(const float*)d_in[16];
  const float* b_hh1     =(const float*)d_in[17];
  const float* W_fc      =(const float*)d_in[18];
  const float* b_fc      =(const float*)d_in[19];
  const int*   sosp      =(const int*)d_in[23];

  float* out = (float*)d_out;
  float* predout = out + (size_t)BB*TT*VV;
  float* ws = (float*)d_ws;

  float* WcatPT = ws;                      // [1024][33024]
  float* Wcat0T = ws + 33816576;           // [1536][4096]
  float* Wcat1T = ws + 40108032;           // [2048][4096]
  float* W1T    = ws + 48496640;           // [512][512]
  float* WinCtxT= ws + 48758784;           // [1024][512]
  float* WattET = ws + 49283072;           // [1024][1024]
  float* encT   = ws + 50331648;           // [1024][16384] (precompute only)
  float* partP  = encT;                    // [4][32][33024] reuses encT region
  float* ep     = ws + 67108864;           // [16384][1024]
  float* encW2  = ws + 83886080;           // [16384][512]
  float* part0  = ws + 92274688;           // [16][32][4096]
  float* part1  = ws + 94371840;           // [16][32][4096]
  float* A0T    = ws + 96468992;           // [1536][32]  = [x ; h0]
  float* A1T    = ws + 96518144;           // [2048][32]  = [h0 ; h1]
  float* c0     = ws + 96583680;
  float* c1     = ws + 96616448;
  float* q      = ws + 96649216;           // legacy (unused in steps)
  float* scores = ws + 96681984;           // [32][512]
  float* argv   = ws + 96698368;           // [500][32]
  int*   argi   = (int*)(ws + 96714368);   // [500][32]
  int*   token  = (int*)(ws + 96730368);   // [32]

  k_init<<<dim3(4833), dim3(256), 0, stream>>>(out, A0T, A1T, c0, c1, q,
      b_att_dec, token, trg, sosp, predout);

  auto TR=[&](const float* src,int ss,float* dst,int ds,int R,int C){
    k_transpose<<<dim3(C/32, R/32), dim3(32,8), 0, stream>>>(src, ss, dst, ds, R, C);
  };
  TR(W_fc, 1024, WcatPT, NPRED, VV, 1024);
  TR(W_att_dec, 1024, WcatPT + VV, NPRED, 1024, 1024);
  TR(W_ih0, 512, Wcat0T, G4, G4, 512);
  TR(W_hh0, 1024, Wcat0T + (size_t)512*G4, G4, G4, 1024);
  TR(W_ih1, 1024, Wcat1T, G4, G4, 1024);
  TR(W_hh1, 1024, Wcat1T + (size_t)1024*G4, G4, G4, 1024);
  TR(W_in, 1536, W1T, 512, 512, 512);
  TR(W_in + 512, 1536, WinCtxT, 512, 512, 1024);
  TR(W_att_enc, 1024, WattET, 1024, 1024, 1024);
  TR(enc_output, 1024, encT, 16384, 16384, 1024);

  k_pregemm<<<dim3(256,8), dim3(256), 0, stream>>>(encT, WattET, b_att_enc, ep, 1024, 1024);
  k_pregemm<<<dim3(256,4), dim3(256), 0, stream>>>(encT, WinCtxT, nullptr, encW2, 512, 1024);

  for (int t=1; t<TT; t++){
    k_score<<<dim3(32,16), dim3(256), 0, stream>>>(ep, partP, b_att_dec, v_att,
        scores, argv, argi, token, predout, t);
    k_attnx<<<dim3(32,8), dim3(256), 0, stream>>>(scores, encW2, emb, token,
        W1T, b_in, A0T);
    k_gemm2<96><<<dim3(16,16), dim3(256), 0, stream>>>(A0T, Wcat0T, part0, G4);
    k_cell<<<dim3(256), dim3(128), 0, stream>>>(part0, b_ih0, b_hh0, c0,
        A0T + (size_t)512*32, A1T);
    k_gemm2<128><<<dim3(16,16), dim3(256), 0, stream>>>(A1T, Wcat1T, part1, G4);
    k_cell<<<dim3(256), dim3(128), 0, stream>>>(part1, b_ih1, b_hh1, c1,
        A1T + (size_t)1024*32, nullptr);
    k_gemm2<256><<<dim3(129,4), dim3(256), 0, stream>>>(A1T + (size_t)1024*32,
        WcatPT, partP, NPRED);
    k_predsum<<<dim3(250), dim3(128), 0, stream>>>(partP, b_fc, out, argv, argi, t);
  }
  k_argfinal<<<dim3(1), dim3(256), 0, stream>>>(argv, argi, predout);
}

// Round 4
// 13062.343 us; speedup vs baseline: 4.0659x; 1.3062x over previous
//
#include <hip/hip_runtime.h>
#include <math.h>

#define BB 32
#define LL 512
#define EE 512
#define HH 1024
#define VV 32000
#define TT 64
#define G4 4096
#define NPRED 33024  // VV + HH

__device__ __forceinline__ float fast_tanh(float x){
  float ax = fabsf(x);
  float e = __expf(ax + ax);
  float r = 1.0f - 2.0f/(e + 1.0f);
  return copysignf(r, x);
}

// ---------------- init ----------------
__global__ void k_init(float* __restrict__ outp, float* __restrict__ a0t,
                       float* __restrict__ a1t, float* __restrict__ c0,
                       float* __restrict__ c1, float* __restrict__ q,
                       const float* __restrict__ bad, int* __restrict__ token,
                       const int* __restrict__ trg, const int* __restrict__ sosp,
                       float* __restrict__ predout){
  int idx = blockIdx.x*256 + threadIdx.x;
  if (idx < 1024000){ int b = idx / VV; int v = idx % VV;
    outp[(size_t)b*TT*VV + v] = 0.f; return; }
  idx -= 1024000;
  if (idx < 49152){ a0t[idx]=0.f; return; } idx -= 49152;
  if (idx < 65536){ a1t[idx]=0.f; return; } idx -= 65536;
  if (idx < 32768){ c0[idx]=0.f; return; } idx -= 32768;
  if (idx < 32768){ c1[idx]=0.f; return; } idx -= 32768;
  if (idx < 32768){ q[idx] = bad[idx & (HH-1)]; return; } idx -= 32768;
  if (idx < 32){ token[idx] = trg[idx*TT]; return; } idx -= 32;
  if (idx < 32){ predout[idx*TT] = (float)(*sosp); return; }
}

// ---------------- generic transpose: dst[c*ds + r] = src[r*ss + c] ----------
__global__ void k_transpose(const float* __restrict__ src, int ss,
                            float* __restrict__ dst, int ds, int R, int C){
  __shared__ float tile[32][33];
  int c0 = blockIdx.x*32, r0 = blockIdx.y*32;
  int tx = threadIdx.x, ty = threadIdx.y;  // (32,8)
  #pragma unroll
  for (int i=0;i<32;i+=8)
    tile[ty+i][tx] = src[(size_t)(r0+ty+i)*ss + c0+tx];
  __syncthreads();
  #pragma unroll
  for (int i=0;i<32;i+=8)
    dst[(size_t)(c0+ty+i)*ds + r0+tx] = tile[tx][ty+i];
}

// ---------------- precompute GEMM: C[m][n] = sum_k AT[k][m]*WT[k][n] (+bias)
__global__ __launch_bounds__(256) void k_pregemm(const float* __restrict__ AT,
    const float* __restrict__ WT, const float* __restrict__ bias,
    float* __restrict__ Cout, int N, int Kdim){
  int mt = blockIdx.x, ntg = blockIdx.y;
  int w = threadIdx.x >> 6, lane = threadIdx.x & 63;
  int m = mt*64 + lane;
  int nbase = ntg*128 + w*32;
  float acc[32];
  #pragma unroll
  for (int j=0;j<32;j++) acc[j]=0.f;
  const float* ap = AT + m;
  const float* wp = WT + nbase;
  for (int k=0;k<Kdim;k++){
    float a = ap[(size_t)k*16384];
    const float4* w4 = (const float4*)(wp + (size_t)k*N);
    #pragma unroll
    for (int j4=0;j4<8;j4++){
      float4 wv = w4[j4];
      acc[j4*4+0] = fmaf(a, wv.x, acc[j4*4+0]);
      acc[j4*4+1] = fmaf(a, wv.y, acc[j4*4+1]);
      acc[j4*4+2] = fmaf(a, wv.z, acc[j4*4+2]);
      acc[j4*4+3] = fmaf(a, wv.w, acc[j4*4+3]);
    }
  }
  __shared__ float tile[64][133];
  #pragma unroll
  for (int j=0;j<32;j++){
    float bv = bias ? bias[nbase+j] : 0.f;
    tile[lane][w*32+j] = acc[j] + bv;
  }
  __syncthreads();
  #pragma unroll
  for (int i=0;i<32;i++){
    int flat = i*256 + threadIdx.x;
    int mm = flat >> 7, nn = flat & 127;
    Cout[(size_t)(mt*64+mm)*N + ntg*128 + nn] = tile[mm][nn];
  }
}

// ---------------- fused: attention scores (blocks 0..511) + predsum(t-1)
// (blocks 512..636). Both depend only on gemmP(t-1); no intra-dispatch deps.
__global__ __launch_bounds__(256) void k_scorepred(const float* __restrict__ ep,
    const float* __restrict__ partP, const float* __restrict__ bad,
    const float* __restrict__ vatt, float* __restrict__ scores,
    const float* __restrict__ b_fc, float* __restrict__ outp,
    float* __restrict__ argv, int* __restrict__ argi, int t){
  int vb = blockIdx.x;
  int w = threadIdx.x >> 6, lane = threadIdx.x & 63;
  if (vb < 512){
    // ---- attention scores for (b, lt) ----
    int b = vb & 31, lt = vb >> 5;
    __shared__ float qs[HH], vs[HH];
    for (int i=threadIdx.x; i<HH; i+=256){
      float qv = bad[i];
      if (t > 1){
        qv += partP[(size_t)b*NPRED + VV + i]
            + partP[(size_t)(32+b)*NPRED + VV + i]
            + partP[(size_t)(64+b)*NPRED + VV + i]
            + partP[(size_t)(96+b)*NPRED + VV + i];
      }
      qs[i] = qv;
      vs[i] = vatt[i];
    }
    __syncthreads();
    #pragma unroll
    for (int i=0;i<8;i++){
      int l = lt*32 + w*8 + i;
      const float4* row = (const float4*)(ep + ((size_t)(b*LL + l))*HH);
      float acc = 0.f;
      #pragma unroll
      for (int c=0;c<4;c++){
        float4 xv = row[c*64 + lane];
        float4 qv = ((const float4*)qs)[c*64 + lane];
        float4 vv = ((const float4*)vs)[c*64 + lane];
        acc += fast_tanh(xv.x+qv.x)*vv.x;
        acc += fast_tanh(xv.y+qv.y)*vv.y;
        acc += fast_tanh(xv.z+qv.z)*vv.z;
        acc += fast_tanh(xv.w+qv.w)*vv.w;
      }
      #pragma unroll
      for (int d=32; d>0; d>>=1) acc += __shfl_down(acc, d);
      if (lane==0) scores[b*LL + l] = acc;
    }
  } else {
    // ---- predsum for step t-1 (skip at t==1: no prior logits) ----
    if (t <= 1) return;
    int pb = vb - 512;                     // 0..124
    int n = pb*256 + threadIdx.x;          // < 32000
    int tm1 = t - 1;
    float bias = b_fc[n];
    const float* p0 = partP + n;
    const float* p1 = partP + (size_t)32*NPRED + n;
    const float* p2 = partP + (size_t)64*NPRED + n;
    const float* p3 = partP + (size_t)96*NPRED + n;
    for (int b=0;b<32;b++){
      float v = p0[(size_t)b*NPRED] + p1[(size_t)b*NPRED]
              + p2[(size_t)b*NPRED] + p3[(size_t)b*NPRED] + bias;
      outp[(size_t)(b*TT + tm1)*VV + n] = v;
      float bv = v; int bi = n;
      #pragma unroll
      for (int d=32; d>0; d>>=1){
        float ov = __shfl_down(bv, d); int oi = __shfl_down(bi, d);
        if (ov > bv || (ov==bv && oi < bi)){ bv=ov; bi=oi; }
      }
      if (lane==0){
        argv[(pb*4 + w)*32 + b] = bv;
        argi[(pb*4 + w)*32 + b] = bi;
      }
    }
  }
}

// ---------------- softmax + token argmax + x = alpha@encW2 + emb@W1T + b_in -
// grid (32 b, 8 et), block 512 (8 waves, each owns a 64-long l/j chunk)
__global__ __launch_bounds__(512) void k_attnx(const float* __restrict__ scores,
    const float* __restrict__ encW2, const float* __restrict__ emb,
    const int* __restrict__ token, const float* __restrict__ W1T,
    const float* __restrict__ b_in, float* __restrict__ A0T,
    const float* __restrict__ argv, const int* __restrict__ argi,
    float* __restrict__ predout, int t){
  int b = blockIdx.x, et = blockIdx.y;
  int tx = threadIdx.x;
  int w = tx >> 6, lane = tx & 63;
  __shared__ float alpha[LL];
  __shared__ float embs[EE];
  __shared__ float redm[8], reds[8];
  __shared__ float comb[8][64];
  __shared__ int tokS;
  // token for this step: argmax of prev logits (t>1), else initial trg token
  if (t > 1){
    if (w==0){
      float bv = -INFINITY; int bi = 0x7fffffff;
      for (int j=lane; j<500; j+=64){
        float v = argv[j*32 + b]; int ix = argi[j*32 + b];
        if (v > bv || (v==bv && ix < bi)){ bv=v; bi=ix; }
      }
      #pragma unroll
      for (int d=32; d>0; d>>=1){
        float ov = __shfl_down(bv, d); int oi = __shfl_down(bi, d);
        if (ov > bv || (ov==bv && oi < bi)){ bv=ov; bi=oi; }
      }
      if (lane==0){
        tokS = bi;
        if (et==0) predout[b*TT + (t-1)] = (float)bi;
      }
    }
  } else if (tx==0) tokS = token[b];
  // softmax over 512 scores (one per thread)
  float s = scores[b*LL + tx];
  float mx = s;
  #pragma unroll
  for (int d=32; d>0; d>>=1) mx = fmaxf(mx, __shfl_down(mx, d));
  if (lane==0) redm[w] = mx;
  __syncthreads();
  mx = redm[0];
  #pragma unroll
  for (int i=1;i<8;i++) mx = fmaxf(mx, redm[i]);
  float e0 = __expf(s - mx);
  float sm = e0;
  #pragma unroll
  for (int d=32; d>0; d>>=1) sm += __shfl_down(sm, d);
  if (lane==0) reds[w] = sm;
  __syncthreads();
  sm = reds[0]+reds[1]+reds[2]+reds[3]+reds[4]+reds[5]+reds[6]+reds[7];
  alpha[tx] = e0 / sm;
  int tok = tokS;                       // valid: __syncthreads above
  embs[tx] = emb[(size_t)tok*EE + tx];  // tx < 512 == EE
  __syncthreads();
  int e = et*64 + lane;
  float acc = 0.f;
  const float* cw = encW2 + (size_t)b*LL*EE + (size_t)w*64*EE + e;
  #pragma unroll 4
  for (int l=0;l<64;l++) acc = fmaf(alpha[w*64+l], cw[(size_t)l*EE], acc);
  const float* wp = W1T + (size_t)w*64*EE + e;
  #pragma unroll 4
  for (int j=0;j<64;j++) acc = fmaf(embs[w*64+j], wp[(size_t)j*EE], acc);
  comb[w][lane] = acc;
  __syncthreads();
  if (w==0){
    float r = comb[0][lane]+comb[1][lane]+comb[2][lane]+comb[3][lane]
            + comb[4][lane]+comb[5][lane]+comb[6][lane]+comb[7][lane] + b_in[e];
    A0T[e*32 + b] = r;
  }
}

// ---------------- 32 FMAs of one W-row against 8 batch values --------------
__device__ __forceinline__ void fma_step(float (&acc)[8][4], const float4 wv,
                                         const float4 a0, const float4 a1){
  acc[0][0]=fmaf(a0.x,wv.x,acc[0][0]); acc[0][1]=fmaf(a0.x,wv.y,acc[0][1]);
  acc[0][2]=fmaf(a0.x,wv.z,acc[0][2]); acc[0][3]=fmaf(a0.x,wv.w,acc[0][3]);
  acc[1][0]=fmaf(a0.y,wv.x,acc[1][0]); acc[1][1]=fmaf(a0.y,wv.y,acc[1][1]);
  acc[1][2]=fmaf(a0.y,wv.z,acc[1][2]); acc[1][3]=fmaf(a0.y,wv.w,acc[1][3]);
  acc[2][0]=fmaf(a0.z,wv.x,acc[2][0]); acc[2][1]=fmaf(a0.z,wv.y,acc[2][1]);
  acc[2][2]=fmaf(a0.z,wv.z,acc[2][2]); acc[2][3]=fmaf(a0.z,wv.w,acc[2][3]);
  acc[3][0]=fmaf(a0.w,wv.x,acc[3][0]); acc[3][1]=fmaf(a0.w,wv.y,acc[3][1]);
  acc[3][2]=fmaf(a0.w,wv.z,acc[3][2]); acc[3][3]=fmaf(a0.w,wv.w,acc[3][3]);
  acc[4][0]=fmaf(a1.x,wv.x,acc[4][0]); acc[4][1]=fmaf(a1.x,wv.y,acc[4][1]);
  acc[4][2]=fmaf(a1.x,wv.z,acc[4][2]); acc[4][3]=fmaf(a1.x,wv.w,acc[4][3]);
  acc[5][0]=fmaf(a1.y,wv.x,acc[5][0]); acc[5][1]=fmaf(a1.y,wv.y,acc[5][1]);
  acc[5][2]=fmaf(a1.y,wv.z,acc[5][2]); acc[5][3]=fmaf(a1.y,wv.w,acc[5][3]);
  acc[6][0]=fmaf(a1.z,wv.x,acc[6][0]); acc[6][1]=fmaf(a1.z,wv.y,acc[6][1]);
  acc[6][2]=fmaf(a1.z,wv.z,acc[6][2]); acc[6][3]=fmaf(a1.z,wv.w,acc[6][3]);
  acc[7][0]=fmaf(a1.w,wv.x,acc[7][0]); acc[7][1]=fmaf(a1.w,wv.y,acc[7][1]);
  acc[7][2]=fmaf(a1.w,wv.z,acc[7][2]); acc[7][3]=fmaf(a1.w,wv.w,acc[7][3]);
}

// ---------------- small-M GEMM v3: LDS A + 4-deep W prefetch pipeline -------
// partial[ks][b][n] = sum_{k in slice} A[k][b] * W[k][n]
// A layout [K][32]; W layout [K][N]. block 256 = 4 waves; wave w -> b in [8w,8w+8)
// lane covers 4 consecutive n. grid (N/256, ksplit). KSLICE % 4 == 0.
// NOTE: no OOB W reads — prefetch stops 1 quad early, tail uses regs.
template<int KSLICE>
__global__ __launch_bounds__(256) void k_gemm2(const float* __restrict__ AT,
    const float* __restrict__ WT, float* __restrict__ partial, int N){
  __shared__ __align__(16) float As[KSLICE*32];
  int nt = blockIdx.x, ks = blockIdx.y;
  int w = threadIdx.x >> 6, lane = threadIdx.x & 63;
  int k0 = ks*KSLICE;
  const float4* asrc = (const float4*)(AT + (size_t)k0*32);
  for (int i=threadIdx.x; i<KSLICE*8; i+=256)
    ((float4*)As)[i] = asrc[i];
  __syncthreads();
  int n0 = nt*256 + lane*4;
  int b0 = w*8;
  float acc[8][4];
  #pragma unroll
  for (int i=0;i<8;i++)
    #pragma unroll
    for (int j=0;j<4;j++) acc[i][j]=0.f;
  const float* wp = WT + (size_t)k0*N + n0;
  const float* ap = As + b0;              // wave-uniform -> LDS broadcast reads
  // preload first quad of W rows (4KB/wave in flight)
  float4 w0 = *(const float4*)(wp);
  float4 w1 = *(const float4*)(wp + (size_t)N);
  float4 w2 = *(const float4*)(wp + (size_t)2*N);
  float4 w3 = *(const float4*)(wp + (size_t)3*N);
  wp += (size_t)4*N;
#define GSTEP(WREG) { float4 a0 = *(const float4*)(ap); \
                      float4 a1 = *(const float4*)(ap+4); ap += 32; \
                      fma_step(acc, WREG, a0, a1); }
  for (int k=0; k<KSLICE-4; k+=4){
    float4 p0 = *(const float4*)(wp);
    float4 p1 = *(const float4*)(wp + (size_t)N);
    float4 p2 = *(const float4*)(wp + (size_t)2*N);
    float4 p3 = *(const float4*)(wp + (size_t)3*N);
    wp += (size_t)4*N;
    GSTEP(w0); GSTEP(w1); GSTEP(w2); GSTEP(w3);
    w0 = p0; w1 = p1; w2 = p2; w3 = p3;
  }
  GSTEP(w0); GSTEP(w1); GSTEP(w2); GSTEP(w3);
#undef GSTEP
  float* pp = partial + ((size_t)ks*32 + b0)*N + n0;
  #pragma unroll
  for (int bi=0;bi<8;bi++)
    *(float4*)(pp + (size_t)bi*N) =
      make_float4(acc[bi][0],acc[bi][1],acc[bi][2],acc[bi][3]);
}

// ---------------- cell update (reduces 32 K-split partials) -----------------
// grid 256 x 128 threads
__global__ __launch_bounds__(128) void k_cell(const float* __restrict__ partial,
    const float* __restrict__ b_ih, const float* __restrict__ b_hh,
    float* __restrict__ c, float* __restrict__ hdst1, float* __restrict__ hdst2){
  int idx = blockIdx.x*128 + threadIdx.x;
  int b = idx >> 10, h = idx & 1023;
  const float* pb = partial + (size_t)b*G4;
  float gi = b_ih[h]      + b_hh[h];
  float gf = b_ih[1024+h] + b_hh[1024+h];
  float gg = b_ih[2048+h] + b_hh[2048+h];
  float go = b_ih[3072+h] + b_hh[3072+h];
  #pragma unroll 8
  for (int ks=0; ks<32; ks++){
    const float* pp = pb + (size_t)ks*32*G4;
    gi += pp[h]; gf += pp[1024+h]; gg += pp[2048+h]; go += pp[3072+h];
  }
  float cv = c[idx];
  float si = 1.f/(1.f+expf(-gi));
  float sf = 1.f/(1.f+expf(-gf));
  float so = 1.f/(1.f+expf(-go));
  float tg = tanhf(gg);
  float c2 = sf*cv + si*tg;
  float h2 = so*tanhf(c2);
  c[idx] = c2;
  hdst1[h*32 + b] = h2;
  if (hdst2) hdst2[h*32 + b] = h2;
}

// ---------------- tail predsum (t=63 only) ----------------------------------
__global__ __launch_bounds__(256) void k_predsum(const float* __restrict__ partP,
    const float* __restrict__ b_fc, float* __restrict__ outp,
    float* __restrict__ argv, int* __restrict__ argi, int t){
  int n = blockIdx.x*256 + threadIdx.x;
  int w = threadIdx.x >> 6, lane = threadIdx.x & 63;
  float bias = b_fc[n];
  const float* p0 = partP + n;
  const float* p1 = partP + (size_t)32*NPRED + n;
  const float* p2 = partP + (size_t)64*NPRED + n;
  const float* p3 = partP + (size_t)96*NPRED + n;
  for (int b=0;b<32;b++){
    float v = p0[(size_t)b*NPRED] + p1[(size_t)b*NPRED]
            + p2[(size_t)b*NPRED] + p3[(size_t)b*NPRED] + bias;
    outp[(size_t)(b*TT + t)*VV + n] = v;
    float bv = v; int bi = n;
    #pragma unroll
    for (int d=32; d>0; d>>=1){
      float ov = __shfl_down(bv, d); int oi = __shfl_down(bi, d);
      if (ov > bv || (ov==bv && oi < bi)){ bv=ov; bi=oi; }
    }
    if (lane==0){
      argv[(blockIdx.x*4 + w)*32 + b] = bv;
      argi[(blockIdx.x*4 + w)*32 + b] = bi;
    }
  }
}

// ---------------- final argmax (step 63) ----------------
__global__ void k_argfinal(const float* __restrict__ argv,
                           const int* __restrict__ argi,
                           float* __restrict__ predout){
  int b = threadIdx.x >> 3, j = threadIdx.x & 7;
  float bv = -INFINITY; int bi = 0x7fffffff;
  for (int p=j; p<500; p+=8){
    float v = argv[p*32+b]; int ix = argi[p*32+b];
    if (v>bv || (v==bv && ix<bi)){ bv=v; bi=ix; }
  }
  #pragma unroll
  for (int d=4; d>0; d>>=1){
    float ov = __shfl_down(bv, d); int oi = __shfl_down(bi, d);
    if (ov>bv || (ov==bv && oi<bi)){ bv=ov; bi=oi; }
  }
  if (j==0) predout[b*TT + 63] = (float)bi;
}

extern "C" void kernel_launch(void* const* d_in, const int* in_sizes, int n_in,
                              void* d_out, int out_size, void* d_ws, size_t ws_size,
                              hipStream_t stream){
  const float* enc_output=(const float*)d_in[0];
  const int*   trg       =(const int*)d_in[1];
  const float* emb       =(const float*)d_in[2];
  const float* W_att_enc =(const float*)d_in[3];
  const float* b_att_enc =(const float*)d_in[4];
  const float* W_att_dec =(const float*)d_in[5];
  const float* b_att_dec =(const float*)d_in[6];
  const float* v_att     =(const float*)d_in[7];
  const float* W_in      =(const float*)d_in[8];
  const float* b_in      =(const float*)d_in[9];
  const float* W_ih0     =(const float*)d_in[10];
  const float* W_hh0     =(const float*)d_in[11];
  const float* b_ih0     =(const float*)d_in[12];
  const float* b_hh0     =(const float*)d_in[13];
  const float* W_ih1     =(const float*)d_in[14];
  const float* W_hh1     =(const float*)d_in[15];
  const float* b_ih1     =(const float*)d_in[16];
  const float* b_hh1     =(const float*)d_in[17];
  const float* W_fc      =(const float*)d_in[18];
  const float* b_fc      =(const float*)d_in[19];
  const int*   sosp      =(const int*)d_in[23];

  float* out = (float*)d_out;
  float* predout = out + (size_t)BB*TT*VV;
  float* ws = (float*)d_ws;

  float* WcatPT = ws;                      // [1024][33024]
  float* Wcat0T = ws + 33816576;           // [1536][4096]
  float* Wcat1T = ws + 40108032;           // [2048][4096]
  float* W1T    = ws + 48496640;           // [512][512]
  float* WinCtxT= ws + 48758784;           // [1024][512]
  float* WattET = ws + 49283072;           // [1024][1024]
  float* encT   = ws + 50331648;           // [1024][16384] (precompute only)
  float* partP  = encT;                    // [4][32][33024] reuses encT region
  float* ep     = ws + 67108864;           // [16384][1024]
  float* encW2  = ws + 83886080;           // [16384][512]
  float* partLS = ws + 92274688;           // [32][32][4096] (spans old part0+part1)
  float* A0T    = ws + 96468992;           // [1536][32]  = [x ; h0]
  float* A1T    = ws + 96518144;           // [2048][32]  = [h0 ; h1]
  float* c0     = ws + 96583680;
  float* c1     = ws + 96616448;
  float* q      = ws + 96649216;           // legacy (unused in steps)
  float* scores = ws + 96681984;           // [32][512]
  float* argv   = ws + 96698368;           // [500][32]
  int*   argi   = (int*)(ws + 96714368);   // [500][32]
  int*   token  = (int*)(ws + 96730368);   // [32]

  k_init<<<dim3(4833), dim3(256), 0, stream>>>(out, A0T, A1T, c0, c1, q,
      b_att_dec, token, trg, sosp, predout);

  auto TR=[&](const float* src,int ss,float* dst,int ds,int R,int C){
    k_transpose<<<dim3(C/32, R/32), dim3(32,8), 0, stream>>>(src, ss, dst, ds, R, C);
  };
  TR(W_fc, 1024, WcatPT, NPRED, VV, 1024);
  TR(W_att_dec, 1024, WcatPT + VV, NPRED, 1024, 1024);
  TR(W_ih0, 512, Wcat0T, G4, G4, 512);
  TR(W_hh0, 1024, Wcat0T + (size_t)512*G4, G4, G4, 1024);
  TR(W_ih1, 1024, Wcat1T, G4, G4, 1024);
  TR(W_hh1, 1024, Wcat1T + (size_t)1024*G4, G4, G4, 1024);
  TR(W_in, 1536, W1T, 512, 512, 512);
  TR(W_in + 512, 1536, WinCtxT, 512, 512, 1024);
  TR(W_att_enc, 1024, WattET, 1024, 1024, 1024);
  TR(enc_output, 1024, encT, 16384, 16384, 1024);

  k_pregemm<<<dim3(256,8), dim3(256), 0, stream>>>(encT, WattET, b_att_enc, ep, 1024, 1024);
  k_pregemm<<<dim3(256,4), dim3(256), 0, stream>>>(encT, WinCtxT, nullptr, encW2, 512, 1024);

  for (int t=1; t<TT; t++){
    k_scorepred<<<dim3(637), dim3(256), 0, stream>>>(ep, partP, b_att_dec, v_att,
        scores, b_fc, out, argv, argi, t);
    k_attnx<<<dim3(32,8), dim3(512), 0, stream>>>(scores, encW2, emb, token,
        W1T, b_in, A0T, argv, argi, predout, t);
    k_gemm2<48><<<dim3(16,32), dim3(256), 0, stream>>>(A0T, Wcat0T, partLS, G4);
    k_cell<<<dim3(256), dim3(128), 0, stream>>>(partLS, b_ih0, b_hh0, c0,
        A0T + (size_t)512*32, A1T);
    k_gemm2<64><<<dim3(16,32), dim3(256), 0, stream>>>(A1T, Wcat1T, partLS, G4);
    k_cell<<<dim3(256), dim3(128), 0, stream>>>(partLS, b_ih1, b_hh1, c1,
        A1T + (size_t)1024*32, nullptr);
    k_gemm2<256><<<dim3(129,4), dim3(256), 0, stream>>>(A1T + (size_t)1024*32,
        WcatPT, partP, NPRED);
  }
  k_predsum<<<dim3(125), dim3(256), 0, stream>>>(partP, b_fc, out, argv, argi, 63);
  k_argfinal<<<dim3(1), dim3(256), 0, stream>>>(argv, argi, predout);
}

// Round 5
// 11673.440 us; speedup vs baseline: 4.5497x; 1.1190x over previous
//
#include <hip/hip_runtime.h>
#include <math.h>

#define BB 32
#define LL 512
#define EE 512
#define HH 1024
#define VV 32000
#define TT 64
#define G4 4096
#define NPRED 33024  // VV + HH

__device__ __forceinline__ float fast_tanh(float x){
  float ax = fabsf(x);
  float e = __expf(ax + ax);
  float r = 1.0f - 2.0f/(e + 1.0f);
  return copysignf(r, x);
}

// ---------------- init ----------------
__global__ void k_init(float* __restrict__ outp, float* __restrict__ a0t,
                       float* __restrict__ a1t, float* __restrict__ c0,
                       float* __restrict__ c1, float* __restrict__ q,
                       const float* __restrict__ bad, int* __restrict__ token,
                       const int* __restrict__ trg, const int* __restrict__ sosp,
                       float* __restrict__ predout){
  int idx = blockIdx.x*256 + threadIdx.x;
  if (idx < 1024000){ int b = idx / VV; int v = idx % VV;
    outp[(size_t)b*TT*VV + v] = 0.f; return; }
  idx -= 1024000;
  if (idx < 49152){ a0t[idx]=0.f; return; } idx -= 49152;
  if (idx < 65536){ a1t[idx]=0.f; return; } idx -= 65536;
  if (idx < 32768){ c0[idx]=0.f; return; } idx -= 32768;
  if (idx < 32768){ c1[idx]=0.f; return; } idx -= 32768;
  if (idx < 32768){ q[idx] = bad[idx & (HH-1)]; return; } idx -= 32768;
  if (idx < 32){ token[idx] = trg[idx*TT]; return; } idx -= 32;
  if (idx < 32){ predout[idx*TT] = (float)(*sosp); return; }
}

// ---------------- generic transpose: dst[c*ds + r] = src[r*ss + c] ----------
__global__ void k_transpose(const float* __restrict__ src, int ss,
                            float* __restrict__ dst, int ds, int R, int C){
  __shared__ float tile[32][33];
  int c0 = blockIdx.x*32, r0 = blockIdx.y*32;
  int tx = threadIdx.x, ty = threadIdx.y;  // (32,8)
  #pragma unroll
  for (int i=0;i<32;i+=8)
    tile[ty+i][tx] = src[(size_t)(r0+ty+i)*ss + c0+tx];
  __syncthreads();
  #pragma unroll
  for (int i=0;i<32;i+=8)
    dst[(size_t)(c0+ty+i)*ds + r0+tx] = tile[tx][ty+i];
}

// ---------------- precompute GEMM v2: 2-m accumulation -----------------------
// C[m][n] = sum_k AT[k][m]*WT[k][n] (+bias). AT is [K][16384].
// block 256 (4 waves); each thread owns m0=mt*128+lane and m0+64, 32 n each.
__global__ __launch_bounds__(256) void k_pregemm(const float* __restrict__ AT,
    const float* __restrict__ WT, const float* __restrict__ bias,
    float* __restrict__ Cout, int N, int Kdim){
  int mt = blockIdx.x, ntg = blockIdx.y;
  int w = threadIdx.x >> 6, lane = threadIdx.x & 63;
  int m0 = mt*128 + lane;
  int nbase = ntg*128 + w*32;
  float acc0[32], acc1[32];
  #pragma unroll
  for (int j=0;j<32;j++){ acc0[j]=0.f; acc1[j]=0.f; }
  const float* ap = AT + m0;
  const float* wp = WT + nbase;
  for (int k=0;k<Kdim;k++){
    float a0 = ap[(size_t)k*16384];
    float a1 = ap[(size_t)k*16384 + 64];
    const float4* w4 = (const float4*)(wp + (size_t)k*N);
    #pragma unroll
    for (int j4=0;j4<8;j4++){
      float4 wv = w4[j4];
      acc0[j4*4+0] = fmaf(a0, wv.x, acc0[j4*4+0]);
      acc0[j4*4+1] = fmaf(a0, wv.y, acc0[j4*4+1]);
      acc0[j4*4+2] = fmaf(a0, wv.z, acc0[j4*4+2]);
      acc0[j4*4+3] = fmaf(a0, wv.w, acc0[j4*4+3]);
      acc1[j4*4+0] = fmaf(a1, wv.x, acc1[j4*4+0]);
      acc1[j4*4+1] = fmaf(a1, wv.y, acc1[j4*4+1]);
      acc1[j4*4+2] = fmaf(a1, wv.z, acc1[j4*4+2]);
      acc1[j4*4+3] = fmaf(a1, wv.w, acc1[j4*4+3]);
    }
  }
  __shared__ float tile[64][133];
  // pass 0: m-half [mt*128 .. mt*128+64)
  #pragma unroll
  for (int j=0;j<32;j++){
    float bv = bias ? bias[nbase+j] : 0.f;
    tile[lane][w*32+j] = acc0[j] + bv;
  }
  __syncthreads();
  #pragma unroll
  for (int i=0;i<32;i++){
    int flat = i*256 + threadIdx.x;
    int mm = flat >> 7, nn = flat & 127;
    Cout[(size_t)(mt*128+mm)*N + ntg*128 + nn] = tile[mm][nn];
  }
  __syncthreads();
  // pass 1: m-half [mt*128+64 .. mt*128+128)
  #pragma unroll
  for (int j=0;j<32;j++){
    float bv = bias ? bias[nbase+j] : 0.f;
    tile[lane][w*32+j] = acc1[j] + bv;
  }
  __syncthreads();
  #pragma unroll
  for (int i=0;i<32;i++){
    int flat = i*256 + threadIdx.x;
    int mm = flat >> 7, nn = flat & 127;
    Cout[(size_t)(mt*128+64+mm)*N + ntg*128 + nn] = tile[mm][nn];
  }
}

// ---------------- fused: attention scores (blocks 0..1023) + predsum(t-1)
// (blocks 1024..1148). Both depend only on gemmP(t-1).
__global__ __launch_bounds__(256) void k_scorepred(const float* __restrict__ ep,
    const float* __restrict__ partP, const float* __restrict__ bad,
    const float* __restrict__ vatt, float* __restrict__ scores,
    const float* __restrict__ b_fc, float* __restrict__ outp,
    float* __restrict__ argv, int* __restrict__ argi, int t){
  int vb = blockIdx.x;
  int w = threadIdx.x >> 6, lane = threadIdx.x & 63;
  if (vb < 1024){
    // ---- attention scores for (b, lt): 16 l-rows per block, 4 per wave ----
    int b = vb & 31, lt = vb >> 5;
    __shared__ float qs[HH], vs[HH];
    for (int i=threadIdx.x; i<HH; i+=256){
      float qv = bad[i];
      if (t > 1){
        qv += partP[(size_t)b*NPRED + VV + i]
            + partP[(size_t)(32+b)*NPRED + VV + i]
            + partP[(size_t)(64+b)*NPRED + VV + i]
            + partP[(size_t)(96+b)*NPRED + VV + i];
      }
      qs[i] = qv;
      vs[i] = vatt[i];
    }
    __syncthreads();
    #pragma unroll
    for (int i=0;i<4;i++){
      int l = lt*16 + w*4 + i;
      const float4* row = (const float4*)(ep + ((size_t)(b*LL + l))*HH);
      float acc = 0.f;
      #pragma unroll
      for (int c=0;c<4;c++){
        float4 xv = row[c*64 + lane];
        float4 qv = ((const float4*)qs)[c*64 + lane];
        float4 vv = ((const float4*)vs)[c*64 + lane];
        acc += fast_tanh(xv.x+qv.x)*vv.x;
        acc += fast_tanh(xv.y+qv.y)*vv.y;
        acc += fast_tanh(xv.z+qv.z)*vv.z;
        acc += fast_tanh(xv.w+qv.w)*vv.w;
      }
      #pragma unroll
      for (int d=32; d>0; d>>=1) acc += __shfl_down(acc, d);
      if (lane==0) scores[b*LL + l] = acc;
    }
  } else {
    // ---- predsum for step t-1 (skip at t==1: no prior logits) ----
    if (t <= 1) return;
    int pb = vb - 1024;                    // 0..124
    int n = pb*256 + threadIdx.x;          // < 32000
    int tm1 = t - 1;
    float bias = b_fc[n];
    const float* p0 = partP + n;
    const float* p1 = partP + (size_t)32*NPRED + n;
    const float* p2 = partP + (size_t)64*NPRED + n;
    const float* p3 = partP + (size_t)96*NPRED + n;
    for (int b=0;b<32;b++){
      float v = p0[(size_t)b*NPRED] + p1[(size_t)b*NPRED]
              + p2[(size_t)b*NPRED] + p3[(size_t)b*NPRED] + bias;
      outp[(size_t)(b*TT + tm1)*VV + n] = v;
      float bv = v; int bi = n;
      #pragma unroll
      for (int d=32; d>0; d>>=1){
        float ov = __shfl_down(bv, d); int oi = __shfl_down(bi, d);
        if (ov > bv || (ov==bv && oi < bi)){ bv=ov; bi=oi; }
      }
      if (lane==0){
        argv[(pb*4 + w)*32 + b] = bv;
        argi[(pb*4 + w)*32 + b] = bi;
      }
    }
  }
}

// ---------------- softmax + token argmax + x = alpha@encW2 + emb@W1T + b_in -
// grid (32 b, 8 et), block 512 (8 waves, each owns a 64-long l/j chunk)
__global__ __launch_bounds__(512) void k_attnx(const float* __restrict__ scores,
    const float* __restrict__ encW2, const float* __restrict__ emb,
    const int* __restrict__ token, const float* __restrict__ W1T,
    const float* __restrict__ b_in, float* __restrict__ A0T,
    const float* __restrict__ argv, const int* __restrict__ argi,
    float* __restrict__ predout, int t){
  int b = blockIdx.x, et = blockIdx.y;
  int tx = threadIdx.x;
  int w = tx >> 6, lane = tx & 63;
  __shared__ float alpha[LL];
  __shared__ float embs[EE];
  __shared__ float redm[8], reds[8];
  __shared__ float comb[8][64];
  __shared__ int tokS;
  // token for this step: argmax of prev logits (t>1), else initial trg token
  if (t > 1){
    if (w==0){
      float bv = -INFINITY; int bi = 0x7fffffff;
      for (int j=lane; j<500; j+=64){
        float v = argv[j*32 + b]; int ix = argi[j*32 + b];
        if (v > bv || (v==bv && ix < bi)){ bv=v; bi=ix; }
      }
      #pragma unroll
      for (int d=32; d>0; d>>=1){
        float ov = __shfl_down(bv, d); int oi = __shfl_down(bi, d);
        if (ov > bv || (ov==bv && oi < bi)){ bv=ov; bi=oi; }
      }
      if (lane==0){
        tokS = bi;
        if (et==0) predout[b*TT + (t-1)] = (float)bi;
      }
    }
  } else if (tx==0) tokS = token[b];
  // softmax over 512 scores (one per thread)
  float s = scores[b*LL + tx];
  float mx = s;
  #pragma unroll
  for (int d=32; d>0; d>>=1) mx = fmaxf(mx, __shfl_down(mx, d));
  if (lane==0) redm[w] = mx;
  __syncthreads();
  mx = redm[0];
  #pragma unroll
  for (int i=1;i<8;i++) mx = fmaxf(mx, redm[i]);
  float e0 = __expf(s - mx);
  float sm = e0;
  #pragma unroll
  for (int d=32; d>0; d>>=1) sm += __shfl_down(sm, d);
  if (lane==0) reds[w] = sm;
  __syncthreads();
  sm = reds[0]+reds[1]+reds[2]+reds[3]+reds[4]+reds[5]+reds[6]+reds[7];
  alpha[tx] = e0 / sm;
  int tok = tokS;                       // valid: __syncthreads above
  embs[tx] = emb[(size_t)tok*EE + tx];  // tx < 512 == EE
  __syncthreads();
  int e = et*64 + lane;
  float acc = 0.f;
  const float* cw = encW2 + (size_t)b*LL*EE + (size_t)w*64*EE + e;
  #pragma unroll 8
  for (int l=0;l<64;l++) acc = fmaf(alpha[w*64+l], cw[(size_t)l*EE], acc);
  const float* wp = W1T + (size_t)w*64*EE + e;
  #pragma unroll 8
  for (int j=0;j<64;j++) acc = fmaf(embs[w*64+j], wp[(size_t)j*EE], acc);
  comb[w][lane] = acc;
  __syncthreads();
  if (w==0){
    float r = comb[0][lane]+comb[1][lane]+comb[2][lane]+comb[3][lane]
            + comb[4][lane]+comb[5][lane]+comb[6][lane]+comb[7][lane] + b_in[e];
    A0T[e*32 + b] = r;
  }
}

// ---------------- 32 FMAs of one W-row against 8 batch values --------------
__device__ __forceinline__ void fma_step(float (&acc)[8][4], const float4 wv,
                                         const float4 a0, const float4 a1){
  acc[0][0]=fmaf(a0.x,wv.x,acc[0][0]); acc[0][1]=fmaf(a0.x,wv.y,acc[0][1]);
  acc[0][2]=fmaf(a0.x,wv.z,acc[0][2]); acc[0][3]=fmaf(a0.x,wv.w,acc[0][3]);
  acc[1][0]=fmaf(a0.y,wv.x,acc[1][0]); acc[1][1]=fmaf(a0.y,wv.y,acc[1][1]);
  acc[1][2]=fmaf(a0.y,wv.z,acc[1][2]); acc[1][3]=fmaf(a0.y,wv.w,acc[1][3]);
  acc[2][0]=fmaf(a0.z,wv.x,acc[2][0]); acc[2][1]=fmaf(a0.z,wv.y,acc[2][1]);
  acc[2][2]=fmaf(a0.z,wv.z,acc[2][2]); acc[2][3]=fmaf(a0.z,wv.w,acc[2][3]);
  acc[3][0]=fmaf(a0.w,wv.x,acc[3][0]); acc[3][1]=fmaf(a0.w,wv.y,acc[3][1]);
  acc[3][2]=fmaf(a0.w,wv.z,acc[3][2]); acc[3][3]=fmaf(a0.w,wv.w,acc[3][3]);
  acc[4][0]=fmaf(a1.x,wv.x,acc[4][0]); acc[4][1]=fmaf(a1.x,wv.y,acc[4][1]);
  acc[4][2]=fmaf(a1.x,wv.z,acc[4][2]); acc[4][3]=fmaf(a1.x,wv.w,acc[4][3]);
  acc[5][0]=fmaf(a1.y,wv.x,acc[5][0]); acc[5][1]=fmaf(a1.y,wv.y,acc[5][1]);
  acc[5][2]=fmaf(a1.y,wv.z,acc[5][2]); acc[5][3]=fmaf(a1.y,wv.w,acc[5][3]);
  acc[6][0]=fmaf(a1.z,wv.x,acc[6][0]); acc[6][1]=fmaf(a1.z,wv.y,acc[6][1]);
  acc[6][2]=fmaf(a1.z,wv.z,acc[6][2]); acc[6][3]=fmaf(a1.z,wv.w,acc[6][3]);
  acc[7][0]=fmaf(a1.w,wv.x,acc[7][0]); acc[7][1]=fmaf(a1.w,wv.y,acc[7][1]);
  acc[7][2]=fmaf(a1.w,wv.z,acc[7][2]); acc[7][3]=fmaf(a1.w,wv.w,acc[7][3]);
}

// ---------------- small-M GEMM v3: LDS A + 4-deep W prefetch pipeline -------
// partial[ks][b][n] = sum_{k in slice} A[k][b] * W[k][n]
template<int KSLICE>
__global__ __launch_bounds__(256) void k_gemm2(const float* __restrict__ AT,
    const float* __restrict__ WT, float* __restrict__ partial, int N){
  __shared__ __align__(16) float As[KSLICE*32];
  int nt = blockIdx.x, ks = blockIdx.y;
  int w = threadIdx.x >> 6, lane = threadIdx.x & 63;
  int k0 = ks*KSLICE;
  const float4* asrc = (const float4*)(AT + (size_t)k0*32);
  for (int i=threadIdx.x; i<KSLICE*8; i+=256)
    ((float4*)As)[i] = asrc[i];
  __syncthreads();
  int n0 = nt*256 + lane*4;
  int b0 = w*8;
  float acc[8][4];
  #pragma unroll
  for (int i=0;i<8;i++)
    #pragma unroll
    for (int j=0;j<4;j++) acc[i][j]=0.f;
  const float* wp = WT + (size_t)k0*N + n0;
  const float* ap = As + b0;
  float4 w0 = *(const float4*)(wp);
  float4 w1 = *(const float4*)(wp + (size_t)N);
  float4 w2 = *(const float4*)(wp + (size_t)2*N);
  float4 w3 = *(const float4*)(wp + (size_t)3*N);
  wp += (size_t)4*N;
#define GSTEP(WREG) { float4 a0 = *(const float4*)(ap); \
                      float4 a1 = *(const float4*)(ap+4); ap += 32; \
                      fma_step(acc, WREG, a0, a1); }
  for (int k=0; k<KSLICE-4; k+=4){
    float4 p0 = *(const float4*)(wp);
    float4 p1 = *(const float4*)(wp + (size_t)N);
    float4 p2 = *(const float4*)(wp + (size_t)2*N);
    float4 p3 = *(const float4*)(wp + (size_t)3*N);
    wp += (size_t)4*N;
    GSTEP(w0); GSTEP(w1); GSTEP(w2); GSTEP(w3);
    w0 = p0; w1 = p1; w2 = p2; w3 = p3;
  }
  GSTEP(w0); GSTEP(w1); GSTEP(w2); GSTEP(w3);
#undef GSTEP
  float* pp = partial + ((size_t)ks*32 + b0)*N + n0;
  #pragma unroll
  for (int bi=0;bi<8;bi++)
    *(float4*)(pp + (size_t)bi*N) =
      make_float4(acc[bi][0],acc[bi][1],acc[bi][2],acc[bi][3]);
}

// ---------------- small-M GEMM v4: 8-deep prefetch (for the 132MB pred W) ---
template<int KSLICE>
__global__ __launch_bounds__(256) void k_gemm2w8(const float* __restrict__ AT,
    const float* __restrict__ WT, float* __restrict__ partial, int N){
  __shared__ __align__(16) float As[KSLICE*32];
  int nt = blockIdx.x, ks = blockIdx.y;
  int w = threadIdx.x >> 6, lane = threadIdx.x & 63;
  int k0 = ks*KSLICE;
  const float4* asrc = (const float4*)(AT + (size_t)k0*32);
  for (int i=threadIdx.x; i<KSLICE*8; i+=256)
    ((float4*)As)[i] = asrc[i];
  __syncthreads();
  int n0 = nt*256 + lane*4;
  int b0 = w*8;
  float acc[8][4];
  #pragma unroll
  for (int i=0;i<8;i++)
    #pragma unroll
    for (int j=0;j<4;j++) acc[i][j]=0.f;
  const float* wp = WT + (size_t)k0*N + n0;
  const float* ap = As + b0;
  float4 w0 = *(const float4*)(wp);
  float4 w1 = *(const float4*)(wp + (size_t)N);
  float4 w2 = *(const float4*)(wp + (size_t)2*N);
  float4 w3 = *(const float4*)(wp + (size_t)3*N);
  float4 w4 = *(const float4*)(wp + (size_t)4*N);
  float4 w5 = *(const float4*)(wp + (size_t)5*N);
  float4 w6 = *(const float4*)(wp + (size_t)6*N);
  float4 w7 = *(const float4*)(wp + (size_t)7*N);
  wp += (size_t)8*N;
#define GSTEP(WREG) { float4 a0 = *(const float4*)(ap); \
                      float4 a1 = *(const float4*)(ap+4); ap += 32; \
                      fma_step(acc, WREG, a0, a1); }
  for (int k=0; k<KSLICE-8; k+=8){
    float4 p0 = *(const float4*)(wp);
    float4 p1 = *(const float4*)(wp + (size_t)N);
    float4 p2 = *(const float4*)(wp + (size_t)2*N);
    float4 p3 = *(const float4*)(wp + (size_t)3*N);
    float4 p4 = *(const float4*)(wp + (size_t)4*N);
    float4 p5 = *(const float4*)(wp + (size_t)5*N);
    float4 p6 = *(const float4*)(wp + (size_t)6*N);
    float4 p7 = *(const float4*)(wp + (size_t)7*N);
    wp += (size_t)8*N;
    GSTEP(w0); GSTEP(w1); GSTEP(w2); GSTEP(w3);
    GSTEP(w4); GSTEP(w5); GSTEP(w6); GSTEP(w7);
    w0=p0; w1=p1; w2=p2; w3=p3; w4=p4; w5=p5; w6=p6; w7=p7;
  }
  GSTEP(w0); GSTEP(w1); GSTEP(w2); GSTEP(w3);
  GSTEP(w4); GSTEP(w5); GSTEP(w6); GSTEP(w7);
#undef GSTEP
  float* pp = partial + ((size_t)ks*32 + b0)*N + n0;
  #pragma unroll
  for (int bi=0;bi<8;bi++)
    *(float4*)(pp + (size_t)bi*N) =
      make_float4(acc[bi][0],acc[bi][1],acc[bi][2],acc[bi][3]);
}

// ---------------- cell update (reduces 32 K-split partials) -----------------
__global__ __launch_bounds__(128) void k_cell(const float* __restrict__ partial,
    const float* __restrict__ b_ih, const float* __restrict__ b_hh,
    float* __restrict__ c, float* __restrict__ hdst1, float* __restrict__ hdst2){
  int idx = blockIdx.x*128 + threadIdx.x;
  int b = idx >> 10, h = idx & 1023;
  const float* pb = partial + (size_t)b*G4;
  float gi = b_ih[h]      + b_hh[h];
  float gf = b_ih[1024+h] + b_hh[1024+h];
  float gg = b_ih[2048+h] + b_hh[2048+h];
  float go = b_ih[3072+h] + b_hh[3072+h];
  #pragma unroll 8
  for (int ks=0; ks<32; ks++){
    const float* pp = pb + (size_t)ks*32*G4;
    gi += pp[h]; gf += pp[1024+h]; gg += pp[2048+h]; go += pp[3072+h];
  }
  float cv = c[idx];
  float si = 1.f/(1.f+expf(-gi));
  float sf = 1.f/(1.f+expf(-gf));
  float so = 1.f/(1.f+expf(-go));
  float tg = tanhf(gg);
  float c2 = sf*cv + si*tg;
  float h2 = so*tanhf(c2);
  c[idx] = c2;
  hdst1[h*32 + b] = h2;
  if (hdst2) hdst2[h*32 + b] = h2;
}

// ---------------- tail predsum (t=63 only) ----------------------------------
__global__ __launch_bounds__(256) void k_predsum(const float* __restrict__ partP,
    const float* __restrict__ b_fc, float* __restrict__ outp,
    float* __restrict__ argv, int* __restrict__ argi, int t){
  int n = blockIdx.x*256 + threadIdx.x;
  int w = threadIdx.x >> 6, lane = threadIdx.x & 63;
  float bias = b_fc[n];
  const float* p0 = partP + n;
  const float* p1 = partP + (size_t)32*NPRED + n;
  const float* p2 = partP + (size_t)64*NPRED + n;
  const float* p3 = partP + (size_t)96*NPRED + n;
  for (int b=0;b<32;b++){
    float v = p0[(size_t)b*NPRED] + p1[(size_t)b*NPRED]
            + p2[(size_t)b*NPRED] + p3[(size_t)b*NPRED] + bias;
    outp[(size_t)(b*TT + t)*VV + n] = v;
    float bv = v; int bi = n;
    #pragma unroll
    for (int d=32; d>0; d>>=1){
      float ov = __shfl_down(bv, d); int oi = __shfl_down(bi, d);
      if (ov > bv || (ov==bv && oi < bi)){ bv=ov; bi=oi; }
    }
    if (lane==0){
      argv[(blockIdx.x*4 + w)*32 + b] = bv;
      argi[(blockIdx.x*4 + w)*32 + b] = bi;
    }
  }
}

// ---------------- final argmax (step 63) ----------------
__global__ void k_argfinal(const float* __restrict__ argv,
                           const int* __restrict__ argi,
                           float* __restrict__ predout){
  int b = threadIdx.x >> 3, j = threadIdx.x & 7;
  float bv = -INFINITY; int bi = 0x7fffffff;
  for (int p=j; p<500; p+=8){
    float v = argv[p*32+b]; int ix = argi[p*32+b];
    if (v>bv || (v==bv && ix<bi)){ bv=v; bi=ix; }
  }
  #pragma unroll
  for (int d=4; d>0; d>>=1){
    float ov = __shfl_down(bv, d); int oi = __shfl_down(bi, d);
    if (ov>bv || (ov==bv && oi<bi)){ bv=ov; bi=oi; }
  }
  if (j==0) predout[b*TT + 63] = (float)bi;
}

extern "C" void kernel_launch(void* const* d_in, const int* in_sizes, int n_in,
                              void* d_out, int out_size, void* d_ws, size_t ws_size,
                              hipStream_t stream){
  const float* enc_output=(const float*)d_in[0];
  const int*   trg       =(const int*)d_in[1];
  const float* emb       =(const float*)d_in[2];
  const float* W_att_enc =(const float*)d_in[3];
  const float* b_att_enc =(const float*)d_in[4];
  const float* W_att_dec =(const float*)d_in[5];
  const float* b_att_dec =(const float*)d_in[6];
  const float* v_att     =(const float*)d_in[7];
  const float* W_in      =(const float*)d_in[8];
  const float* b_in      =(const float*)d_in[9];
  const float* W_ih0     =(const float*)d_in[10];
  const float* W_hh0     =(const float*)d_in[11];
  const float* b_ih0     =(const float*)d_in[12];
  const float* b_hh0     =(const float*)d_in[13];
  const float* W_ih1     =(const float*)d_in[14];
  const float* W_hh1     =(const float*)d_in[15];
  const float* b_ih1     =(const float*)d_in[16];
  const float* b_hh1     =(const float*)d_in[17];
  const float* W_fc      =(const float*)d_in[18];
  const float* b_fc      =(const float*)d_in[19];
  const int*   sosp      =(const int*)d_in[23];

  float* out = (float*)d_out;
  float* predout = out + (size_t)BB*TT*VV;
  float* ws = (float*)d_ws;

  float* WcatPT = ws;                      // [1024][33024]
  float* Wcat0T = ws + 33816576;           // [1536][4096]
  float* Wcat1T = ws + 40108032;           // [2048][4096]
  float* W1T    = ws + 48496640;           // [512][512]
  float* WinCtxT= ws + 48758784;           // [1024][512]
  float* WattET = ws + 49283072;           // [1024][1024]
  float* encT   = ws + 50331648;           // [1024][16384] (precompute only)
  float* partP  = encT;                    // [4][32][33024] reuses encT region
  float* ep     = ws + 67108864;           // [16384][1024]
  float* encW2  = ws + 83886080;           // [16384][512]
  float* partLS = ws + 92274688;           // [32][32][4096]
  float* A0T    = ws + 96468992;           // [1536][32]  = [x ; h0]
  float* A1T    = ws + 96518144;           // [2048][32]  = [h0 ; h1]
  float* c0     = ws + 96583680;
  float* c1     = ws + 96616448;
  float* q      = ws + 96649216;           // legacy (unused in steps)
  float* scores = ws + 96681984;           // [32][512]
  float* argv   = ws + 96698368;           // [500][32]
  int*   argi   = (int*)(ws + 96714368);   // [500][32]
  int*   token  = (int*)(ws + 96730368);   // [32]

  k_init<<<dim3(4833), dim3(256), 0, stream>>>(out, A0T, A1T, c0, c1, q,
      b_att_dec, token, trg, sosp, predout);

  auto TR=[&](const float* src,int ss,float* dst,int ds,int R,int C){
    k_transpose<<<dim3(C/32, R/32), dim3(32,8), 0, stream>>>(src, ss, dst, ds, R, C);
  };
  TR(W_fc, 1024, WcatPT, NPRED, VV, 1024);
  TR(W_att_dec, 1024, WcatPT + VV, NPRED, 1024, 1024);
  TR(W_ih0, 512, Wcat0T, G4, G4, 512);
  TR(W_hh0, 1024, Wcat0T + (size_t)512*G4, G4, G4, 1024);
  TR(W_ih1, 1024, Wcat1T, G4, G4, 1024);
  TR(W_hh1, 1024, Wcat1T + (size_t)1024*G4, G4, G4, 1024);
  TR(W_in, 1536, W1T, 512, 512, 512);
  TR(W_in + 512, 1536, WinCtxT, 512, 512, 1024);
  TR(W_att_enc, 1024, WattET, 1024, 1024, 1024);
  TR(enc_output, 1024, encT, 16384, 16384, 1024);

  k_pregemm<<<dim3(128,8), dim3(256), 0, stream>>>(encT, WattET, b_att_enc, ep, 1024, 1024);
  k_pregemm<<<dim3(128,4), dim3(256), 0, stream>>>(encT, WinCtxT, nullptr, encW2, 512, 1024);

  for (int t=1; t<TT; t++){
    k_scorepred<<<dim3(1149), dim3(256), 0, stream>>>(ep, partP, b_att_dec, v_att,
        scores, b_fc, out, argv, argi, t);
    k_attnx<<<dim3(32,8), dim3(512), 0, stream>>>(scores, encW2, emb, token,
        W1T, b_in, A0T, argv, argi, predout, t);
    k_gemm2<48><<<dim3(16,32), dim3(256), 0, stream>>>(A0T, Wcat0T, partLS, G4);
    k_cell<<<dim3(256), dim3(128), 0, stream>>>(partLS, b_ih0, b_hh0, c0,
        A0T + (size_t)512*32, A1T);
    k_gemm2<64><<<dim3(16,32), dim3(256), 0, stream>>>(A1T, Wcat1T, partLS, G4);
    k_cell<<<dim3(256), dim3(128), 0, stream>>>(partLS, b_ih1, b_hh1, c1,
        A1T + (size_t)1024*32, nullptr);
    k_gemm2w8<256><<<dim3(129,4), dim3(256), 0, stream>>>(A1T + (size_t)1024*32,
        WcatPT, partP, NPRED);
  }
  k_predsum<<<dim3(125), dim3(256), 0, stream>>>(partP, b_fc, out, argv, argi, 63);
  k_argfinal<<<dim3(1), dim3(256), 0, stream>>>(argv, argi, predout);
}

// Round 6
// 11035.759 us; speedup vs baseline: 4.8126x; 1.0578x over previous
//
#include <hip/hip_runtime.h>
#include <math.h>

#define BB 32
#define LL 512
#define EE 512
#define HH 1024
#define VV 32000
#define TT 64
#define G4 4096
#define NPRED 33024  // VV + HH

__device__ __forceinline__ float fast_tanh(float x){
  float ax = fabsf(x);
  float e = __expf(ax + ax);
  float r = 1.0f - 2.0f/(e + 1.0f);
  return copysignf(r, x);
}

// ---------------- init ----------------
__global__ void k_init(float* __restrict__ outp, float* __restrict__ a0t,
                       float* __restrict__ a1t, float* __restrict__ c0,
                       float* __restrict__ c1, float* __restrict__ q,
                       const float* __restrict__ bad, int* __restrict__ token,
                       const int* __restrict__ trg, const int* __restrict__ sosp,
                       float* __restrict__ predout){
  int idx = blockIdx.x*256 + threadIdx.x;
  if (idx < 1024000){ int b = idx / VV; int v = idx % VV;
    outp[(size_t)b*TT*VV + v] = 0.f; return; }
  idx -= 1024000;
  if (idx < 49152){ a0t[idx]=0.f; return; } idx -= 49152;
  if (idx < 65536){ a1t[idx]=0.f; return; } idx -= 65536;
  if (idx < 32768){ c0[idx]=0.f; return; } idx -= 32768;
  if (idx < 32768){ c1[idx]=0.f; return; } idx -= 32768;
  if (idx < 32768){ q[idx] = bad[idx & (HH-1)]; return; } idx -= 32768;
  if (idx < 32){ token[idx] = trg[idx*TT]; return; } idx -= 32;
  if (idx < 32){ predout[idx*TT] = (float)(*sosp); return; }
}

// ---------------- generic transpose: dst[c*ds + r] = src[r*ss + c] ----------
__global__ void k_transpose(const float* __restrict__ src, int ss,
                            float* __restrict__ dst, int ds, int R, int C){
  __shared__ float tile[32][33];
  int c0 = blockIdx.x*32, r0 = blockIdx.y*32;
  int tx = threadIdx.x, ty = threadIdx.y;  // (32,8)
  #pragma unroll
  for (int i=0;i<32;i+=8)
    tile[ty+i][tx] = src[(size_t)(r0+ty+i)*ss + c0+tx];
  __syncthreads();
  #pragma unroll
  for (int i=0;i<32;i+=8)
    dst[(size_t)(c0+ty+i)*ds + r0+tx] = tile[tx][ty+i];
}

// ---------------- transpose + pack into block-contiguous GEMM tiles ---------
// logical W^T[k][n] with k = kOff + src-col, n = nOff + src-row.
// packed addr = ((ks*NT + nt)*KSLICE + kk)*256 + j ; ks=k/KSLICE, nt=n>>8.
__global__ void k_transpack(const float* __restrict__ src, int ss,
                            float* __restrict__ dst, int KS, int NT,
                            int kOff, int nOff){
  __shared__ float tile[32][33];
  int c0 = blockIdx.x*32, r0 = blockIdx.y*32;
  int tx = threadIdx.x, ty = threadIdx.y;  // (32,8)
  #pragma unroll
  for (int i=0;i<32;i+=8)
    tile[ty+i][tx] = src[(size_t)(r0+ty+i)*ss + c0+tx];
  __syncthreads();
  #pragma unroll
  for (int i=0;i<32;i+=8){
    int k = kOff + c0 + ty + i;
    int n = nOff + r0 + tx;
    int ks = k / KS, kk = k - ks*KS;
    dst[((size_t)(ks*NT + (n>>8))*KS + kk)*256 + (n&255)] = tile[tx][ty+i];
  }
}

// ---------------- precompute GEMM v2: 2-m accumulation -----------------------
__global__ __launch_bounds__(256) void k_pregemm(const float* __restrict__ AT,
    const float* __restrict__ WT, const float* __restrict__ bias,
    float* __restrict__ Cout, int N, int Kdim){
  int mt = blockIdx.x, ntg = blockIdx.y;
  int w = threadIdx.x >> 6, lane = threadIdx.x & 63;
  int m0 = mt*128 + lane;
  int nbase = ntg*128 + w*32;
  float acc0[32], acc1[32];
  #pragma unroll
  for (int j=0;j<32;j++){ acc0[j]=0.f; acc1[j]=0.f; }
  const float* ap = AT + m0;
  const float* wp = WT + nbase;
  for (int k=0;k<Kdim;k++){
    float a0 = ap[(size_t)k*16384];
    float a1 = ap[(size_t)k*16384 + 64];
    const float4* w4 = (const float4*)(wp + (size_t)k*N);
    #pragma unroll
    for (int j4=0;j4<8;j4++){
      float4 wv = w4[j4];
      acc0[j4*4+0] = fmaf(a0, wv.x, acc0[j4*4+0]);
      acc0[j4*4+1] = fmaf(a0, wv.y, acc0[j4*4+1]);
      acc0[j4*4+2] = fmaf(a0, wv.z, acc0[j4*4+2]);
      acc0[j4*4+3] = fmaf(a0, wv.w, acc0[j4*4+3]);
      acc1[j4*4+0] = fmaf(a1, wv.x, acc1[j4*4+0]);
      acc1[j4*4+1] = fmaf(a1, wv.y, acc1[j4*4+1]);
      acc1[j4*4+2] = fmaf(a1, wv.z, acc1[j4*4+2]);
      acc1[j4*4+3] = fmaf(a1, wv.w, acc1[j4*4+3]);
    }
  }
  __shared__ float tile[64][133];
  #pragma unroll
  for (int j=0;j<32;j++){
    float bv = bias ? bias[nbase+j] : 0.f;
    tile[lane][w*32+j] = acc0[j] + bv;
  }
  __syncthreads();
  #pragma unroll
  for (int i=0;i<32;i++){
    int flat = i*256 + threadIdx.x;
    int mm = flat >> 7, nn = flat & 127;
    Cout[(size_t)(mt*128+mm)*N + ntg*128 + nn] = tile[mm][nn];
  }
  __syncthreads();
  #pragma unroll
  for (int j=0;j<32;j++){
    float bv = bias ? bias[nbase+j] : 0.f;
    tile[lane][w*32+j] = acc1[j] + bv;
  }
  __syncthreads();
  #pragma unroll
  for (int i=0;i<32;i++){
    int flat = i*256 + threadIdx.x;
    int mm = flat >> 7, nn = flat & 127;
    Cout[(size_t)(mt*128+64+mm)*N + ntg*128 + nn] = tile[mm][nn];
  }
}

// ---------------- fused: attention scores (blocks 0..1023) + predsum(t-1)
__global__ __launch_bounds__(256) void k_scorepred(const float* __restrict__ ep,
    const float* __restrict__ partP, const float* __restrict__ bad,
    const float* __restrict__ vatt, float* __restrict__ scores,
    const float* __restrict__ b_fc, float* __restrict__ outp,
    float* __restrict__ argv, int* __restrict__ argi, int t){
  int vb = blockIdx.x;
  int w = threadIdx.x >> 6, lane = threadIdx.x & 63;
  if (vb < 1024){
    int b = vb & 31, lt = vb >> 5;
    __shared__ float qs[HH], vs[HH];
    for (int i=threadIdx.x; i<HH; i+=256){
      float qv = bad[i];
      if (t > 1){
        qv += partP[(size_t)b*NPRED + VV + i]
            + partP[(size_t)(32+b)*NPRED + VV + i]
            + partP[(size_t)(64+b)*NPRED + VV + i]
            + partP[(size_t)(96+b)*NPRED + VV + i];
      }
      qs[i] = qv;
      vs[i] = vatt[i];
    }
    __syncthreads();
    #pragma unroll
    for (int i=0;i<4;i++){
      int l = lt*16 + w*4 + i;
      const float4* row = (const float4*)(ep + ((size_t)(b*LL + l))*HH);
      float acc = 0.f;
      #pragma unroll
      for (int c=0;c<4;c++){
        float4 xv = row[c*64 + lane];
        float4 qv = ((const float4*)qs)[c*64 + lane];
        float4 vv = ((const float4*)vs)[c*64 + lane];
        acc += fast_tanh(xv.x+qv.x)*vv.x;
        acc += fast_tanh(xv.y+qv.y)*vv.y;
        acc += fast_tanh(xv.z+qv.z)*vv.z;
        acc += fast_tanh(xv.w+qv.w)*vv.w;
      }
      #pragma unroll
      for (int d=32; d>0; d>>=1) acc += __shfl_down(acc, d);
      if (lane==0) scores[b*LL + l] = acc;
    }
  } else {
    if (t <= 1) return;
    int pb = vb - 1024;                    // 0..124
    int n = pb*256 + threadIdx.x;          // < 32000
    int tm1 = t - 1;
    float bias = b_fc[n];
    const float* p0 = partP + n;
    const float* p1 = partP + (size_t)32*NPRED + n;
    const float* p2 = partP + (size_t)64*NPRED + n;
    const float* p3 = partP + (size_t)96*NPRED + n;
    for (int b=0;b<32;b++){
      float v = p0[(size_t)b*NPRED] + p1[(size_t)b*NPRED]
              + p2[(size_t)b*NPRED] + p3[(size_t)b*NPRED] + bias;
      outp[(size_t)(b*TT + tm1)*VV + n] = v;
      float bv = v; int bi = n;
      #pragma unroll
      for (int d=32; d>0; d>>=1){
        float ov = __shfl_down(bv, d); int oi = __shfl_down(bi, d);
        if (ov > bv || (ov==bv && oi < bi)){ bv=ov; bi=oi; }
      }
      if (lane==0){
        argv[(pb*4 + w)*32 + b] = bv;
        argi[(pb*4 + w)*32 + b] = bi;
      }
    }
  }
}

// ---------------- softmax + token argmax + x = alpha@encW2 + emb@W1T + b_in -
__global__ __launch_bounds__(512) void k_attnx(const float* __restrict__ scores,
    const float* __restrict__ encW2, const float* __restrict__ emb,
    const int* __restrict__ token, const float* __restrict__ W1T,
    const float* __restrict__ b_in, float* __restrict__ A0T,
    const float* __restrict__ argv, const int* __restrict__ argi,
    float* __restrict__ predout, int t){
  int b = blockIdx.x, et = blockIdx.y;
  int tx = threadIdx.x;
  int w = tx >> 6, lane = tx & 63;
  __shared__ float alpha[LL];
  __shared__ float embs[EE];
  __shared__ float redm[8], reds[8];
  __shared__ float comb[8][64];
  __shared__ int tokS;
  if (t > 1){
    if (w==0){
      float bv = -INFINITY; int bi = 0x7fffffff;
      for (int j=lane; j<500; j+=64){
        float v = argv[j*32 + b]; int ix = argi[j*32 + b];
        if (v > bv || (v==bv && ix < bi)){ bv=v; bi=ix; }
      }
      #pragma unroll
      for (int d=32; d>0; d>>=1){
        float ov = __shfl_down(bv, d); int oi = __shfl_down(bi, d);
        if (ov > bv || (ov==bv && oi < bi)){ bv=ov; bi=oi; }
      }
      if (lane==0){
        tokS = bi;
        if (et==0) predout[b*TT + (t-1)] = (float)bi;
      }
    }
  } else if (tx==0) tokS = token[b];
  float s = scores[b*LL + tx];
  float mx = s;
  #pragma unroll
  for (int d=32; d>0; d>>=1) mx = fmaxf(mx, __shfl_down(mx, d));
  if (lane==0) redm[w] = mx;
  __syncthreads();
  mx = redm[0];
  #pragma unroll
  for (int i=1;i<8;i++) mx = fmaxf(mx, redm[i]);
  float e0 = __expf(s - mx);
  float sm = e0;
  #pragma unroll
  for (int d=32; d>0; d>>=1) sm += __shfl_down(sm, d);
  if (lane==0) reds[w] = sm;
  __syncthreads();
  sm = reds[0]+reds[1]+reds[2]+reds[3]+reds[4]+reds[5]+reds[6]+reds[7];
  alpha[tx] = e0 / sm;
  int tok = tokS;
  embs[tx] = emb[(size_t)tok*EE + tx];
  __syncthreads();
  int e = et*64 + lane;
  float acc = 0.f;
  const float* cw = encW2 + (size_t)b*LL*EE + (size_t)w*64*EE + e;
  #pragma unroll 8
  for (int l=0;l<64;l++) acc = fmaf(alpha[w*64+l], cw[(size_t)l*EE], acc);
  const float* wp = W1T + (size_t)w*64*EE + e;
  #pragma unroll 8
  for (int j=0;j<64;j++) acc = fmaf(embs[w*64+j], wp[(size_t)j*EE], acc);
  comb[w][lane] = acc;
  __syncthreads();
  if (w==0){
    float r = comb[0][lane]+comb[1][lane]+comb[2][lane]+comb[3][lane]
            + comb[4][lane]+comb[5][lane]+comb[6][lane]+comb[7][lane] + b_in[e];
    A0T[e*32 + b] = r;
  }
}

// ---------------- 32 FMAs of one W-row against 8 batch values --------------
__device__ __forceinline__ void fma_step(float (&acc)[8][4], const float4 wv,
                                         const float4 a0, const float4 a1){
  acc[0][0]=fmaf(a0.x,wv.x,acc[0][0]); acc[0][1]=fmaf(a0.x,wv.y,acc[0][1]);
  acc[0][2]=fmaf(a0.x,wv.z,acc[0][2]); acc[0][3]=fmaf(a0.x,wv.w,acc[0][3]);
  acc[1][0]=fmaf(a0.y,wv.x,acc[1][0]); acc[1][1]=fmaf(a0.y,wv.y,acc[1][1]);
  acc[1][2]=fmaf(a0.y,wv.z,acc[1][2]); acc[1][3]=fmaf(a0.y,wv.w,acc[1][3]);
  acc[2][0]=fmaf(a0.z,wv.x,acc[2][0]); acc[2][1]=fmaf(a0.z,wv.y,acc[2][1]);
  acc[2][2]=fmaf(a0.z,wv.z,acc[2][2]); acc[2][3]=fmaf(a0.z,wv.w,acc[2][3]);
  acc[3][0]=fmaf(a0.w,wv.x,acc[3][0]); acc[3][1]=fmaf(a0.w,wv.y,acc[3][1]);
  acc[3][2]=fmaf(a0.w,wv.z,acc[3][2]); acc[3][3]=fmaf(a0.w,wv.w,acc[3][3]);
  acc[4][0]=fmaf(a1.x,wv.x,acc[4][0]); acc[4][1]=fmaf(a1.x,wv.y,acc[4][1]);
  acc[4][2]=fmaf(a1.x,wv.z,acc[4][2]); acc[4][3]=fmaf(a1.x,wv.w,acc[4][3]);
  acc[5][0]=fmaf(a1.y,wv.x,acc[5][0]); acc[5][1]=fmaf(a1.y,wv.y,acc[5][1]);
  acc[5][2]=fmaf(a1.y,wv.z,acc[5][2]); acc[5][3]=fmaf(a1.y,wv.w,acc[5][3]);
  acc[6][0]=fmaf(a1.z,wv.x,acc[6][0]); acc[6][1]=fmaf(a1.z,wv.y,acc[6][1]);
  acc[6][2]=fmaf(a1.z,wv.z,acc[6][2]); acc[6][3]=fmaf(a1.z,wv.w,acc[6][3]);
  acc[7][0]=fmaf(a1.w,wv.x,acc[7][0]); acc[7][1]=fmaf(a1.w,wv.y,acc[7][1]);
  acc[7][2]=fmaf(a1.w,wv.z,acc[7][2]); acc[7][3]=fmaf(a1.w,wv.w,acc[7][3]);
}

// ---------------- small-M GEMM v5: packed-tile W, sequential stream, 8-deep -
// partial[ks][b][n] = sum_{k in slice} A[k][b] * Wpacked tile(ks,nt)[k][j]
// tile base = (ks*NT + nt)*KSLICE*256 ; row stride = 256 floats (1KB).
template<int KSLICE>
__global__ __launch_bounds__(256) void k_gemm3(const float* __restrict__ AT,
    const float* __restrict__ WP, float* __restrict__ partial, int N, int NT){
  __shared__ __align__(16) float As[KSLICE*32];
  int nt = blockIdx.x, ks = blockIdx.y;
  int w = threadIdx.x >> 6, lane = threadIdx.x & 63;
  int k0 = ks*KSLICE;
  const float4* asrc = (const float4*)(AT + (size_t)k0*32);
  for (int i=threadIdx.x; i<KSLICE*8; i+=256)
    ((float4*)As)[i] = asrc[i];
  __syncthreads();
  int n0 = nt*256 + lane*4;
  int b0 = w*8;
  float acc[8][4];
  #pragma unroll
  for (int i=0;i<8;i++)
    #pragma unroll
    for (int j=0;j<4;j++) acc[i][j]=0.f;
  const float* wp = WP + (size_t)(ks*NT + nt)*KSLICE*256 + lane*4;
  const float* ap = As + b0;
  float4 w0 = *(const float4*)(wp);
  float4 w1 = *(const float4*)(wp + 256);
  float4 w2 = *(const float4*)(wp + 512);
  float4 w3 = *(const float4*)(wp + 768);
  float4 w4 = *(const float4*)(wp + 1024);
  float4 w5 = *(const float4*)(wp + 1280);
  float4 w6 = *(const float4*)(wp + 1536);
  float4 w7 = *(const float4*)(wp + 1792);
  wp += 2048;
#define GSTEP(WREG) { float4 a0 = *(const float4*)(ap); \
                      float4 a1 = *(const float4*)(ap+4); ap += 32; \
                      fma_step(acc, WREG, a0, a1); }
  for (int k=0; k<KSLICE-8; k+=8){
    float4 p0 = *(const float4*)(wp);
    float4 p1 = *(const float4*)(wp + 256);
    float4 p2 = *(const float4*)(wp + 512);
    float4 p3 = *(const float4*)(wp + 768);
    float4 p4 = *(const float4*)(wp + 1024);
    float4 p5 = *(const float4*)(wp + 1280);
    float4 p6 = *(const float4*)(wp + 1536);
    float4 p7 = *(const float4*)(wp + 1792);
    wp += 2048;
    GSTEP(w0); GSTEP(w1); GSTEP(w2); GSTEP(w3);
    GSTEP(w4); GSTEP(w5); GSTEP(w6); GSTEP(w7);
    w0=p0; w1=p1; w2=p2; w3=p3; w4=p4; w5=p5; w6=p6; w7=p7;
  }
  GSTEP(w0); GSTEP(w1); GSTEP(w2); GSTEP(w3);
  GSTEP(w4); GSTEP(w5); GSTEP(w6); GSTEP(w7);
#undef GSTEP
  float* pp = partial + ((size_t)ks*32 + b0)*N + n0;
  #pragma unroll
  for (int bi=0;bi<8;bi++)
    *(float4*)(pp + (size_t)bi*N) =
      make_float4(acc[bi][0],acc[bi][1],acc[bi][2],acc[bi][3]);
}

// ---------------- cell update (reduces 32 K-split partials) -----------------
__global__ __launch_bounds__(128) void k_cell(const float* __restrict__ partial,
    const float* __restrict__ b_ih, const float* __restrict__ b_hh,
    float* __restrict__ c, float* __restrict__ hdst1, float* __restrict__ hdst2){
  int idx = blockIdx.x*128 + threadIdx.x;
  int b = idx >> 10, h = idx & 1023;
  const float* pb = partial + (size_t)b*G4;
  float gi = b_ih[h]      + b_hh[h];
  float gf = b_ih[1024+h] + b_hh[1024+h];
  float gg = b_ih[2048+h] + b_hh[2048+h];
  float go = b_ih[3072+h] + b_hh[3072+h];
  #pragma unroll 8
  for (int ks=0; ks<32; ks++){
    const float* pp = pb + (size_t)ks*32*G4;
    gi += pp[h]; gf += pp[1024+h]; gg += pp[2048+h]; go += pp[3072+h];
  }
  float cv = c[idx];
  float si = 1.f/(1.f+expf(-gi));
  float sf = 1.f/(1.f+expf(-gf));
  float so = 1.f/(1.f+expf(-go));
  float tg = tanhf(gg);
  float c2 = sf*cv + si*tg;
  float h2 = so*tanhf(c2);
  c[idx] = c2;
  hdst1[h*32 + b] = h2;
  if (hdst2) hdst2[h*32 + b] = h2;
}

// ---------------- tail predsum (t=63 only) ----------------------------------
__global__ __launch_bounds__(256) void k_predsum(const float* __restrict__ partP,
    const float* __restrict__ b_fc, float* __restrict__ outp,
    float* __restrict__ argv, int* __restrict__ argi, int t){
  int n = blockIdx.x*256 + threadIdx.x;
  int w = threadIdx.x >> 6, lane = threadIdx.x & 63;
  float bias = b_fc[n];
  const float* p0 = partP + n;
  const float* p1 = partP + (size_t)32*NPRED + n;
  const float* p2 = partP + (size_t)64*NPRED + n;
  const float* p3 = partP + (size_t)96*NPRED + n;
  for (int b=0;b<32;b++){
    float v = p0[(size_t)b*NPRED] + p1[(size_t)b*NPRED]
            + p2[(size_t)b*NPRED] + p3[(size_t)b*NPRED] + bias;
    outp[(size_t)(b*TT + t)*VV + n] = v;
    float bv = v; int bi = n;
    #pragma unroll
    for (int d=32; d>0; d>>=1){
      float ov = __shfl_down(bv, d); int oi = __shfl_down(bi, d);
      if (ov > bv || (ov==bv && oi < bi)){ bv=ov; bi=oi; }
    }
    if (lane==0){
      argv[(blockIdx.x*4 + w)*32 + b] = bv;
      argi[(blockIdx.x*4 + w)*32 + b] = bi;
    }
  }
}

// ---------------- final argmax (step 63) ----------------
__global__ void k_argfinal(const float* __restrict__ argv,
                           const int* __restrict__ argi,
                           float* __restrict__ predout){
  int b = threadIdx.x >> 3, j = threadIdx.x & 7;
  float bv = -INFINITY; int bi = 0x7fffffff;
  for (int p=j; p<500; p+=8){
    float v = argv[p*32+b]; int ix = argi[p*32+b];
    if (v>bv || (v==bv && ix<bi)){ bv=v; bi=ix; }
  }
  #pragma unroll
  for (int d=4; d>0; d>>=1){
    float ov = __shfl_down(bv, d); int oi = __shfl_down(bi, d);
    if (ov>bv || (ov==bv && oi<bi)){ bv=ov; bi=oi; }
  }
  if (j==0) predout[b*TT + 63] = (float)bi;
}

extern "C" void kernel_launch(void* const* d_in, const int* in_sizes, int n_in,
                              void* d_out, int out_size, void* d_ws, size_t ws_size,
                              hipStream_t stream){
  const float* enc_output=(const float*)d_in[0];
  const int*   trg       =(const int*)d_in[1];
  const float* emb       =(const float*)d_in[2];
  const float* W_att_enc =(const float*)d_in[3];
  const float* b_att_enc =(const float*)d_in[4];
  const float* W_att_dec =(const float*)d_in[5];
  const float* b_att_dec =(const float*)d_in[6];
  const float* v_att     =(const float*)d_in[7];
  const float* W_in      =(const float*)d_in[8];
  const float* b_in      =(const float*)d_in[9];
  const float* W_ih0     =(const float*)d_in[10];
  const float* W_hh0     =(const float*)d_in[11];
  const float* b_ih0     =(const float*)d_in[12];
  const float* b_hh0     =(const float*)d_in[13];
  const float* W_ih1     =(const float*)d_in[14];
  const float* W_hh1     =(const float*)d_in[15];
  const float* b_ih1     =(const float*)d_in[16];
  const float* b_hh1     =(const float*)d_in[17];
  const float* W_fc      =(const float*)d_in[18];
  const float* b_fc      =(const float*)d_in[19];
  const int*   sosp      =(const int*)d_in[23];

  float* out = (float*)d_out;
  float* predout = out + (size_t)BB*TT*VV;
  float* ws = (float*)d_ws;

  float* WPackP = ws;                      // packed [4ks][129nt][256][256]
  float* WPack0 = ws + 33816576;           // packed [32ks][16nt][48][256]
  float* WPack1 = ws + 40108032;           // packed [32ks][16nt][64][256]
  float* W1T    = ws + 48496640;           // [512][512]
  float* WinCtxT= ws + 48758784;           // [1024][512]
  float* WattET = ws + 49283072;           // [1024][1024]
  float* encT   = ws + 50331648;           // [1024][16384] (precompute only)
  float* partP  = encT;                    // [4][32][33024] reuses encT region
  float* ep     = ws + 67108864;           // [16384][1024]
  float* encW2  = ws + 83886080;           // [16384][512]
  float* partLS = ws + 92274688;           // [32][32][4096]
  float* A0T    = ws + 96468992;           // [1536][32]  = [x ; h0]
  float* A1T    = ws + 96518144;           // [2048][32]  = [h0 ; h1]
  float* c0     = ws + 96583680;
  float* c1     = ws + 96616448;
  float* q      = ws + 96649216;           // legacy (unused in steps)
  float* scores = ws + 96681984;           // [32][512]
  float* argv   = ws + 96698368;           // [500][32]
  int*   argi   = (int*)(ws + 96714368);   // [500][32]
  int*   token  = (int*)(ws + 96730368);   // [32]

  k_init<<<dim3(4833), dim3(256), 0, stream>>>(out, A0T, A1T, c0, c1, q,
      b_att_dec, token, trg, sosp, predout);

  auto TR=[&](const float* src,int ss,float* dst,int ds,int R,int C){
    k_transpose<<<dim3(C/32, R/32), dim3(32,8), 0, stream>>>(src, ss, dst, ds, R, C);
  };
  auto TP=[&](const float* src,int ss,float* dst,int KS,int NT,int kOff,int nOff,
              int R,int C){
    k_transpack<<<dim3(C/32, R/32), dim3(32,8), 0, stream>>>(src, ss, dst,
        KS, NT, kOff, nOff);
  };
  // packed GEMM weights (transpose + tile-pack, same allocations/sizes)
  TP(W_fc,      1024, WPackP, 256, 129, 0,    0,  VV,   1024);
  TP(W_att_dec, 1024, WPackP, 256, 129, 0,    VV, 1024, 1024);
  TP(W_ih0,     512,  WPack0, 48,  16,  0,    0,  G4,   512);
  TP(W_hh0,     1024, WPack0, 48,  16,  512,  0,  G4,   1024);
  TP(W_ih1,     1024, WPack1, 64,  16,  0,    0,  G4,   1024);
  TP(W_hh1,     1024, WPack1, 64,  16,  1024, 0,  G4,   1024);
  // plain transposes for precompute / attnx
  TR(W_in, 1536, W1T, 512, 512, 512);
  TR(W_in + 512, 1536, WinCtxT, 512, 512, 1024);
  TR(W_att_enc, 1024, WattET, 1024, 1024, 1024);
  TR(enc_output, 1024, encT, 16384, 16384, 1024);

  k_pregemm<<<dim3(128,8), dim3(256), 0, stream>>>(encT, WattET, b_att_enc, ep, 1024, 1024);
  k_pregemm<<<dim3(128,4), dim3(256), 0, stream>>>(encT, WinCtxT, nullptr, encW2, 512, 1024);

  for (int t=1; t<TT; t++){
    k_scorepred<<<dim3(1149), dim3(256), 0, stream>>>(ep, partP, b_att_dec, v_att,
        scores, b_fc, out, argv, argi, t);
    k_attnx<<<dim3(32,8), dim3(512), 0, stream>>>(scores, encW2, emb, token,
        W1T, b_in, A0T, argv, argi, predout, t);
    k_gemm3<48><<<dim3(16,32), dim3(256), 0, stream>>>(A0T, WPack0, partLS, G4, 16);
    k_cell<<<dim3(256), dim3(128), 0, stream>>>(partLS, b_ih0, b_hh0, c0,
        A0T + (size_t)512*32, A1T);
    k_gemm3<64><<<dim3(16,32), dim3(256), 0, stream>>>(A1T, WPack1, partLS, G4, 16);
    k_cell<<<dim3(256), dim3(128), 0, stream>>>(partLS, b_ih1, b_hh1, c1,
        A1T + (size_t)1024*32, nullptr);
    k_gemm3<256><<<dim3(129,4), dim3(256), 0, stream>>>(A1T + (size_t)1024*32,
        WPackP, partP, NPRED, 129);
  }
  k_predsum<<<dim3(125), dim3(256), 0, stream>>>(partP, b_fc, out, argv, argi, 63);
  k_argfinal<<<dim3(1), dim3(256), 0, stream>>>(argv, argi, predout);
}